// Round 1
// baseline (296.221 us; speedup 1.0000x reference)
//
#include <hip/hip_runtime.h>

#define DEVINL __device__ __forceinline__

using bf16x8 = __attribute__((ext_vector_type(8))) short;
using f32x4  = __attribute__((ext_vector_type(4))) float;

constexpr int Bb = 8, Ls = 1024, DM = 768, NH = 12, DH = 64;
constexpr int QKV = 3 * DM; // 2304

DEVINL unsigned short f2bf(float f) {
    union { float f; unsigned u; } v; v.f = f;
    unsigned r = v.u + 0x7FFFu + ((v.u >> 16) & 1u);
    return (unsigned short)(r >> 16);
}
DEVINL float bf2f(unsigned short h) {
    union { unsigned u; float f; } v; v.u = ((unsigned)h) << 16; return v.f;
}

DEVINL void gload_lds16(const void* g, void* l) {
    __builtin_amdgcn_global_load_lds((const __attribute__((address_space(1))) void*)g,
                                     (__attribute__((address_space(3))) void*)l, 16, 0, 0);
}

// ---------------- prep: casts + rope table ----------------
__global__ void prep_kernel(const float* __restrict__ x, const float* __restrict__ wq,
                            const float* __restrict__ wo,
                            unsigned short* __restrict__ xb, unsigned short* __restrict__ wqb,
                            unsigned short* __restrict__ wob, float* __restrict__ tab) {
    const int X4 = Bb * Ls * DM / 4, W4 = QKV * DM / 4, O4 = DM * DM / 4, TB = Ls * DH;
    const int total = X4 + W4 + O4 + TB;
    for (int idx = blockIdx.x * blockDim.x + threadIdx.x; idx < total;
         idx += gridDim.x * blockDim.x) {
        if (idx < X4 + W4 + O4) {
            const float4* s; unsigned short* d; int i;
            if (idx < X4)            { s = (const float4*)x;  d = xb;  i = idx; }
            else if (idx < X4 + W4)  { s = (const float4*)wq; d = wqb; i = idx - X4; }
            else                     { s = (const float4*)wo; d = wob; i = idx - X4 - W4; }
            float4 v = s[i];
            ushort4 o;
            o.x = f2bf(v.x); o.y = f2bf(v.y); o.z = f2bf(v.z); o.w = f2bf(v.w);
            ((ushort4*)d)[i] = o;
        } else {
            int r = idx - (X4 + W4 + O4);
            int l = r >> 6, c = r & 63, i = c & 31;
            float freq = powf(10000.0f, -(float)i / 32.0f);
            float ang = (float)l * freq;
            tab[l * 64 + c] = (c < 32) ? cosf(ang) : sinf(ang);
        }
    }
}

// ---------------- bf16 NT GEMM: C = A(MxK) * B(NxK)^T + bias ----------------
// 128x128 tile, BK=32, 4 waves (2x2), 4x4 16x16x32 MFMA frags per wave.
// LDS tiles staged via global_load_lds with source-pre-swizzled addresses
// (XOR chunk^(row&3)) so fragment ds_read_b128 is only 4-way conflicted.
template <int OUT_BF16>
__global__ __launch_bounds__(256) void gemm_nt(const unsigned short* __restrict__ A,
                                               const unsigned short* __restrict__ Bw,
                                               const float* __restrict__ bias,
                                               void* __restrict__ Cout,
                                               int M, int Nn, int K) {
    __shared__ unsigned short As[128 * 32];
    __shared__ unsigned short Bs[128 * 32];
    const int tid = threadIdx.x, lane = tid & 63, w = tid >> 6;
    const int bm = blockIdx.x * 128, bn = blockIdx.y * 128;
    const int wm = w >> 1, wn = w & 1;
    const int col = lane & 15, q4 = lane >> 4;
    f32x4 acc[4][4] = {};
    for (int kb = 0; kb < K; kb += 32) {
#pragma unroll
        for (int i = 0; i < 2; ++i) {
            int c0 = w * 128 + i * 64;
            int p = c0 + lane;
            int row = p >> 2;
            int kc = (p & 3) ^ (row & 3);   // source pre-swizzle
            gload_lds16(A + (size_t)(bm + row) * K + kb + kc * 8, &As[c0 * 8]);
            gload_lds16(Bw + (size_t)(bn + row) * K + kb + kc * 8, &Bs[c0 * 8]);
        }
        __syncthreads();
        bf16x8 af[4], bfr[4];
#pragma unroll
        for (int t = 0; t < 4; ++t) {
            int ra = wm * 64 + t * 16 + col;
            int rb = wn * 64 + t * 16 + col;
            af[t]  = *(const bf16x8*)&As[(ra * 32 + q4 * 8) ^ ((ra & 3) << 3)];
            bfr[t] = *(const bf16x8*)&Bs[(rb * 32 + q4 * 8) ^ ((rb & 3) << 3)];
        }
#pragma unroll
        for (int t = 0; t < 4; ++t)
#pragma unroll
            for (int u = 0; u < 4; ++u)
                acc[t][u] = __builtin_amdgcn_mfma_f32_16x16x32_bf16(af[t], bfr[u], acc[t][u], 0, 0, 0);
        __syncthreads();
    }
#pragma unroll
    for (int t = 0; t < 4; ++t) {
        int grow_base = bm + wm * 64 + t * 16 + q4 * 4;
#pragma unroll
        for (int u = 0; u < 4; ++u) {
            int gcol = bn + wn * 64 + u * 16 + col;
            float bv = bias[gcol];
#pragma unroll
            for (int r = 0; r < 4; ++r) {
                float vv = acc[t][u][r] + bv;
                if (OUT_BF16)
                    ((unsigned short*)Cout)[(size_t)(grow_base + r) * Nn + gcol] = f2bf(vv);
                else
                    ((float*)Cout)[(size_t)(grow_base + r) * Nn + gcol] = vv;
            }
        }
    }
}

// ---------------- RoPE + repack q,k to (B,N,L,D), q scaled 1/8 ----------------
__global__ void rope_qk(const unsigned short* __restrict__ qkvb, const float* __restrict__ tab,
                        unsigned short* __restrict__ qs, unsigned short* __restrict__ ks) {
    const int b = blockIdx.z, n = blockIdx.y;
    const int idx = blockIdx.x * blockDim.x + threadIdx.x; // [0, 8192)
    const int l = idx >> 3, d8 = idx & 7;
    const unsigned short* src = qkvb + (size_t)(b * Ls + l) * QKV + n * DH + d8 * 8;
    float4 cs = *(const float4*)&tab[l * 64 + d8 * 4];
    float4 sn = *(const float4*)&tab[l * 64 + 32 + d8 * 4];
    float cv[4] = {cs.x, cs.y, cs.z, cs.w};
    float sv[4] = {sn.x, sn.y, sn.z, sn.w};
    size_t dsto = ((size_t)(b * NH + n) * Ls + l) * DH + d8 * 8;
    {
        bf16x8 qv = *(const bf16x8*)src;
        bf16x8 ov;
#pragma unroll
        for (int j = 0; j < 4; ++j) {
            float x1 = bf2f((unsigned short)qv[2 * j]), x2 = bf2f((unsigned short)qv[2 * j + 1]);
            ov[2 * j]     = (short)f2bf((x1 * cv[j] - x2 * sv[j]) * 0.125f);
            ov[2 * j + 1] = (short)f2bf((x2 * cv[j] + x1 * sv[j]) * 0.125f);
        }
        *(bf16x8*)(qs + dsto) = ov;
    }
    {
        bf16x8 kv = *(const bf16x8*)(src + DM);
        bf16x8 ov;
#pragma unroll
        for (int j = 0; j < 4; ++j) {
            float x1 = bf2f((unsigned short)kv[2 * j]), x2 = bf2f((unsigned short)kv[2 * j + 1]);
            ov[2 * j]     = (short)f2bf(x1 * cv[j] - x2 * sv[j]);
            ov[2 * j + 1] = (short)f2bf(x2 * cv[j] + x1 * sv[j]);
        }
        *(bf16x8*)(ks + dsto) = ov;
    }
}

// ---------------- V transpose: (B,L,N,D) slice -> vt (B,N,D,L) ----------------
__global__ void vtrans(const unsigned short* __restrict__ qkvb, unsigned short* __restrict__ vt) {
    __shared__ unsigned short vsh[64][72];
    const int b = blockIdx.z, n = blockIdx.y, lt = blockIdx.x;
    const int tid = threadIdx.x;
#pragma unroll
    for (int i = 0; i < 2; ++i) {
        int c = tid + i * 256;
        int lrow = c >> 3, d8 = c & 7;
        *(bf16x8*)&vsh[lrow][d8 * 8] =
            *(const bf16x8*)(qkvb + (size_t)(b * Ls + lt * 64 + lrow) * QKV + 2 * DM + n * DH + d8 * 8);
    }
    __syncthreads();
#pragma unroll
    for (int i = 0; i < 2; ++i) {
        int c = tid + i * 256;
        int d = c >> 3, l8 = c & 7;
        bf16x8 v;
#pragma unroll
        for (int j = 0; j < 8; ++j) v[j] = (short)vsh[l8 * 8 + j][d];
        *(bf16x8*)(vt + ((size_t)(b * NH + n) * DH + d) * Ls + lt * 64 + l8 * 8) = v;
    }
}

// ---------------- flash attention with pos_bias + key mask ----------------
// grid (L/64, NH, B); 4 waves x 16 q-rows; KT=64; K/V^T in XOR-swizzled LDS.
__global__ __launch_bounds__(256) void attn_kernel(const unsigned short* __restrict__ qs,
                                                   const unsigned short* __restrict__ ks,
                                                   const unsigned short* __restrict__ vt,
                                                   const float* __restrict__ posb,
                                                   const int* __restrict__ mask,
                                                   unsigned short* __restrict__ ob) {
    __shared__ unsigned short Ksh[64 * 64];
    __shared__ unsigned short Vsh[64 * 64];
    __shared__ unsigned short Psh[4][16 * 64];
    __shared__ float maskb[Ls];
    const int b = blockIdx.z, n = blockIdx.y, qt = blockIdx.x;
    const int tid = threadIdx.x, lane = tid & 63, w = tid >> 6;
    const int col = lane & 15, q4 = lane >> 4;
    for (int i = tid; i < Ls; i += 256)
        maskb[i] = (mask[b * Ls + i] > 0) ? 0.0f : -1e30f;
    const unsigned short* qbn = qs + (size_t)(b * NH + n) * Ls * DH;
    const unsigned short* kbn = ks + (size_t)(b * NH + n) * Ls * DH;
    const unsigned short* vbn = vt + (size_t)(b * NH + n) * DH * Ls;
    const float* pb = posb + (size_t)n * Ls * Ls;
    bf16x8 qf[2];
#pragma unroll
    for (int j = 0; j < 2; ++j)
        qf[j] = *(const bf16x8*)(qbn + (size_t)(qt * 64 + w * 16 + col) * DH + q4 * 8 + j * 32);
    const int qrow_c = w * 16 + q4 * 4; // rows owned in C-layout
    float mrun[4], lrun[4];
    f32x4 oacc[4];
#pragma unroll
    for (int r = 0; r < 4; ++r) { mrun[r] = -1e30f; lrun[r] = 0.f; }
#pragma unroll
    for (int t = 0; t < 4; ++t) oacc[t] = f32x4{0.f, 0.f, 0.f, 0.f};

    for (int kt = 0; kt < Ls / 64; ++kt) {
        // stage K (64x64) and V^T (64x64), source pre-swizzled chunk^(row&7)
#pragma unroll
        for (int i = 0; i < 2; ++i) {
            int c0 = w * 128 + i * 64;
            int p = c0 + lane;
            int row = p >> 3, cin = (p & 7) ^ (row & 7);
            gload_lds16(kbn + (size_t)(kt * 64 + row) * DH + cin * 8, &Ksh[c0 * 8]);
            gload_lds16(vbn + (size_t)row * Ls + kt * 64 + cin * 8, &Vsh[c0 * 8]);
        }
        __syncthreads();
        // S = Q K^T
        f32x4 s[4];
#pragma unroll
        for (int t = 0; t < 4; ++t) {
            s[t] = f32x4{0.f, 0.f, 0.f, 0.f};
            int krow = t * 16 + col;
#pragma unroll
            for (int j = 0; j < 2; ++j) {
                bf16x8 kf = *(const bf16x8*)&Ksh[(krow * 64 + q4 * 8 + j * 32) ^ ((krow & 7) << 3)];
                s[t] = __builtin_amdgcn_mfma_f32_16x16x32_bf16(qf[j], kf, s[t], 0, 0, 0);
            }
        }
        // bias + mask
        float svv[4][4];
#pragma unroll
        for (int t = 0; t < 4; ++t) {
            int kg = kt * 64 + t * 16 + col;
            float mb = maskb[kg];
#pragma unroll
            for (int r = 0; r < 4; ++r) {
                int qg = qt * 64 + qrow_c + r;
                svv[t][r] = s[t][r] + pb[(size_t)qg * Ls + kg] + mb;
            }
        }
        // online softmax (row stats across the 16 lanes of each quarter)
        float pm[4], al[4];
#pragma unroll
        for (int r = 0; r < 4; ++r) {
            pm[r] = fmaxf(fmaxf(svv[0][r], svv[1][r]), fmaxf(svv[2][r], svv[3][r]));
#pragma unroll
            for (int msk = 1; msk < 16; msk <<= 1)
                pm[r] = fmaxf(pm[r], __shfl_xor(pm[r], msk));
            float mn = fmaxf(mrun[r], pm[r]);
            al[r] = __expf(mrun[r] - mn);
            mrun[r] = mn;
        }
        float p[4][4], ps[4];
#pragma unroll
        for (int r = 0; r < 4; ++r) ps[r] = 0.f;
#pragma unroll
        for (int t = 0; t < 4; ++t)
#pragma unroll
            for (int r = 0; r < 4; ++r) {
                p[t][r] = __expf(svv[t][r] - mrun[r]);
                ps[r] += p[t][r];
            }
#pragma unroll
        for (int r = 0; r < 4; ++r) {
#pragma unroll
            for (int msk = 1; msk < 16; msk <<= 1)
                ps[r] += __shfl_xor(ps[r], msk);
            lrun[r] = lrun[r] * al[r] + ps[r];
        }
#pragma unroll
        for (int t = 0; t < 4; ++t)
#pragma unroll
            for (int r = 0; r < 4; ++r) oacc[t][r] *= al[r];
        // P -> LDS (swizzled), then O += P V
        unsigned short* pw = Psh[w];
#pragma unroll
        for (int t = 0; t < 4; ++t)
#pragma unroll
            for (int r = 0; r < 4; ++r) {
                int row = q4 * 4 + r;
                pw[(row * 64 + t * 16 + col) ^ ((row & 7) << 3)] = f2bf(p[t][r]);
            }
#pragma unroll
        for (int ot = 0; ot < 4; ++ot) {
            int vrow = ot * 16 + col;
#pragma unroll
            for (int j = 0; j < 2; ++j) {
                bf16x8 pa = *(const bf16x8*)&pw[(col * 64 + q4 * 8 + j * 32) ^ ((col & 7) << 3)];
                bf16x8 vb = *(const bf16x8*)&Vsh[(vrow * 64 + q4 * 8 + j * 32) ^ ((vrow & 7) << 3)];
                oacc[ot] = __builtin_amdgcn_mfma_f32_16x16x32_bf16(pa, vb, oacc[ot], 0, 0, 0);
            }
        }
        __syncthreads();
    }
    // epilogue: normalize and write o in (B, L, N*D) bf16
#pragma unroll
    for (int r = 0; r < 4; ++r) {
        int lg = qt * 64 + qrow_c + r;
        float inv = 1.0f / lrun[r];
#pragma unroll
        for (int ot = 0; ot < 4; ++ot)
            ob[(size_t)(b * Ls + lg) * DM + n * DH + ot * 16 + col] = f2bf(oacc[ot][r] * inv);
    }
}

extern "C" void kernel_launch(void* const* d_in, const int* in_sizes, int n_in,
                              void* d_out, int out_size, void* d_ws, size_t ws_size,
                              hipStream_t stream) {
    const float* x     = (const float*)d_in[0];
    const float* posb  = (const float*)d_in[1];
    const float* qkv_w = (const float*)d_in[2];
    const float* qkv_b = (const float*)d_in[3];
    const float* out_w = (const float*)d_in[4];
    const float* out_b = (const float*)d_in[5];
    const int*   mask  = (const int*)d_in[6];
    float* out = (float*)d_out;

    char* wp = (char*)d_ws;
    auto alloc = [&](size_t bytes) {
        char* p = wp;
        wp += (bytes + 255) & ~(size_t)255;
        return p;
    };
    unsigned short* xb   = (unsigned short*)alloc((size_t)Bb * Ls * DM * 2);
    unsigned short* wqb  = (unsigned short*)alloc((size_t)QKV * DM * 2);
    unsigned short* wob  = (unsigned short*)alloc((size_t)DM * DM * 2);
    float*          tab  = (float*)alloc((size_t)Ls * DH * 4);
    unsigned short* qkvb = (unsigned short*)alloc((size_t)Bb * Ls * QKV * 2);
    unsigned short* qsb  = (unsigned short*)alloc((size_t)Bb * NH * Ls * DH * 2);
    unsigned short* ksb  = (unsigned short*)alloc((size_t)Bb * NH * Ls * DH * 2);
    unsigned short* vtb  = (unsigned short*)alloc((size_t)Bb * NH * DH * Ls * 2);
    unsigned short* obb  = (unsigned short*)alloc((size_t)Bb * Ls * DM * 2);

    prep_kernel<<<dim3(2048), dim3(256), 0, stream>>>(x, qkv_w, out_w, xb, wqb, wob, tab);
    gemm_nt<1><<<dim3(64, 18), dim3(256), 0, stream>>>(xb, wqb, qkv_b, (void*)qkvb, Bb * Ls, QKV, DM);
    rope_qk<<<dim3(32, NH, Bb), dim3(256), 0, stream>>>(qkvb, tab, qsb, ksb);
    vtrans<<<dim3(16, NH, Bb), dim3(256), 0, stream>>>(qkvb, vtb);
    attn_kernel<<<dim3(16, NH, Bb), dim3(256), 0, stream>>>(qsb, ksb, vtb, posb, mask, obb);
    gemm_nt<0><<<dim3(64, 6), dim3(256), 0, stream>>>(obb, wob, out_b, (void*)out, Bb * Ls, DM, DM);
}

// Round 2
// 294.158 us; speedup vs baseline: 1.0070x; 1.0070x over previous
//
#include <hip/hip_runtime.h>

#define DEVINL __device__ __forceinline__

using bf16x8 = __attribute__((ext_vector_type(8))) short;
using f32x4  = __attribute__((ext_vector_type(4))) float;

constexpr int Bb = 8, Ls = 1024, DM = 768, NH = 12, DH = 64;
constexpr int QKV = 3 * DM; // 2304

DEVINL unsigned short f2bf(float f) {
    union { float f; unsigned u; } v; v.f = f;
    unsigned r = v.u + 0x7FFFu + ((v.u >> 16) & 1u);
    return (unsigned short)(r >> 16);
}
DEVINL float bf2f(unsigned short h) {
    union { unsigned u; float f; } v; v.u = ((unsigned)h) << 16; return v.f;
}

DEVINL void gload_lds16(const void* g, void* l) {
    __builtin_amdgcn_global_load_lds((const __attribute__((address_space(1))) void*)g,
                                     (__attribute__((address_space(3))) void*)l, 16, 0, 0);
}

// ---------------- prep: casts + exp(pos_bias) + rope table ----------------
__global__ void prep_kernel(const float* __restrict__ x, const float* __restrict__ wq,
                            const float* __restrict__ wo, const float* __restrict__ pbias,
                            unsigned short* __restrict__ xb, unsigned short* __restrict__ wqb,
                            unsigned short* __restrict__ wob, unsigned short* __restrict__ ebb,
                            float* __restrict__ tab) {
    const int X4 = Bb * Ls * DM / 4, W4 = QKV * DM / 4, O4 = DM * DM / 4;
    const int E4 = NH * Ls * Ls / 4, TB = Ls * DH;
    const int total = X4 + W4 + O4 + E4 + TB;
    for (int idx = blockIdx.x * blockDim.x + threadIdx.x; idx < total;
         idx += gridDim.x * blockDim.x) {
        if (idx < X4 + W4 + O4) {
            const float4* s; unsigned short* d; int i;
            if (idx < X4)            { s = (const float4*)x;  d = xb;  i = idx; }
            else if (idx < X4 + W4)  { s = (const float4*)wq; d = wqb; i = idx - X4; }
            else                     { s = (const float4*)wo; d = wob; i = idx - X4 - W4; }
            float4 v = s[i];
            ushort4 o;
            o.x = f2bf(v.x); o.y = f2bf(v.y); o.z = f2bf(v.z); o.w = f2bf(v.w);
            ((ushort4*)d)[i] = o;
        } else if (idx < X4 + W4 + O4 + E4) {
            int i = idx - (X4 + W4 + O4);
            float4 v = ((const float4*)pbias)[i];
            ushort4 o;
            o.x = f2bf(__expf(v.x)); o.y = f2bf(__expf(v.y));
            o.z = f2bf(__expf(v.z)); o.w = f2bf(__expf(v.w));
            ((ushort4*)ebb)[i] = o;
        } else {
            int r = idx - (X4 + W4 + O4 + E4);
            int l = r >> 6, c = r & 63, i = c & 31;
            float freq = powf(10000.0f, -(float)i / 32.0f);
            float ang = (float)l * freq;
            tab[l * 64 + c] = (c < 32) ? cosf(ang) : sinf(ang);
        }
    }
}

// ---------------- bf16 NT GEMM: C = A(MxK) * B(NxK)^T + bias ----------------
template <int OUT_BF16>
__global__ __launch_bounds__(256) void gemm_nt(const unsigned short* __restrict__ A,
                                               const unsigned short* __restrict__ Bw,
                                               const float* __restrict__ bias,
                                               void* __restrict__ Cout,
                                               int M, int Nn, int K) {
    __shared__ unsigned short As[128 * 32];
    __shared__ unsigned short Bs[128 * 32];
    const int tid = threadIdx.x, lane = tid & 63, w = tid >> 6;
    const int bm = blockIdx.x * 128, bn = blockIdx.y * 128;
    const int wm = w >> 1, wn = w & 1;
    const int col = lane & 15, q4 = lane >> 4;
    f32x4 acc[4][4] = {};
    for (int kb = 0; kb < K; kb += 32) {
#pragma unroll
        for (int i = 0; i < 2; ++i) {
            int c0 = w * 128 + i * 64;
            int p = c0 + lane;
            int row = p >> 2;
            int kc = (p & 3) ^ (row & 3);   // source pre-swizzle
            gload_lds16(A + (size_t)(bm + row) * K + kb + kc * 8, &As[c0 * 8]);
            gload_lds16(Bw + (size_t)(bn + row) * K + kb + kc * 8, &Bs[c0 * 8]);
        }
        __syncthreads();
        bf16x8 af[4], bfr[4];
#pragma unroll
        for (int t = 0; t < 4; ++t) {
            int ra = wm * 64 + t * 16 + col;
            int rb = wn * 64 + t * 16 + col;
            af[t]  = *(const bf16x8*)&As[(ra * 32 + q4 * 8) ^ ((ra & 3) << 3)];
            bfr[t] = *(const bf16x8*)&Bs[(rb * 32 + q4 * 8) ^ ((rb & 3) << 3)];
        }
#pragma unroll
        for (int t = 0; t < 4; ++t)
#pragma unroll
            for (int u = 0; u < 4; ++u)
                acc[t][u] = __builtin_amdgcn_mfma_f32_16x16x32_bf16(af[t], bfr[u], acc[t][u], 0, 0, 0);
        __syncthreads();
    }
#pragma unroll
    for (int t = 0; t < 4; ++t) {
        int grow_base = bm + wm * 64 + t * 16 + q4 * 4;
#pragma unroll
        for (int u = 0; u < 4; ++u) {
            int gcol = bn + wn * 64 + u * 16 + col;
            float bv = bias[gcol];
#pragma unroll
            for (int r = 0; r < 4; ++r) {
                float vv = acc[t][u][r] + bv;
                if (OUT_BF16)
                    ((unsigned short*)Cout)[(size_t)(grow_base + r) * Nn + gcol] = f2bf(vv);
                else
                    ((float*)Cout)[(size_t)(grow_base + r) * Nn + gcol] = vv;
            }
        }
    }
}

// ---------------- RoPE + repack q,k to (B,N,L,D); q scaled by log2e/8 ----------------
__global__ void rope_qk(const unsigned short* __restrict__ qkvb, const float* __restrict__ tab,
                        unsigned short* __restrict__ qs, unsigned short* __restrict__ ks) {
    const int b = blockIdx.z, n = blockIdx.y;
    const int idx = blockIdx.x * blockDim.x + threadIdx.x; // [0, 8192)
    const int l = idx >> 3, d8 = idx & 7;
    const float QSCL = 0.125f * 1.44269504089f;
    const unsigned short* src = qkvb + (size_t)(b * Ls + l) * QKV + n * DH + d8 * 8;
    float4 cs = *(const float4*)&tab[l * 64 + d8 * 4];
    float4 sn = *(const float4*)&tab[l * 64 + 32 + d8 * 4];
    float cv[4] = {cs.x, cs.y, cs.z, cs.w};
    float sv[4] = {sn.x, sn.y, sn.z, sn.w};
    size_t dsto = ((size_t)(b * NH + n) * Ls + l) * DH + d8 * 8;
    {
        bf16x8 qv = *(const bf16x8*)src;
        bf16x8 ov;
#pragma unroll
        for (int j = 0; j < 4; ++j) {
            float x1 = bf2f((unsigned short)qv[2 * j]), x2 = bf2f((unsigned short)qv[2 * j + 1]);
            ov[2 * j]     = (short)f2bf((x1 * cv[j] - x2 * sv[j]) * QSCL);
            ov[2 * j + 1] = (short)f2bf((x2 * cv[j] + x1 * sv[j]) * QSCL);
        }
        *(bf16x8*)(qs + dsto) = ov;
    }
    {
        bf16x8 kv = *(const bf16x8*)(src + DM);
        bf16x8 ov;
#pragma unroll
        for (int j = 0; j < 4; ++j) {
            float x1 = bf2f((unsigned short)kv[2 * j]), x2 = bf2f((unsigned short)kv[2 * j + 1]);
            ov[2 * j]     = (short)f2bf(x1 * cv[j] - x2 * sv[j]);
            ov[2 * j + 1] = (short)f2bf(x2 * cv[j] + x1 * sv[j]);
        }
        *(bf16x8*)(ks + dsto) = ov;
    }
}

// ---------------- V transpose: (B,L,N,D) slice -> vt (B,N,D,L) ----------------
__global__ void vtrans(const unsigned short* __restrict__ qkvb, unsigned short* __restrict__ vt) {
    __shared__ unsigned short vsh[64][72];
    const int b = blockIdx.z, n = blockIdx.y, lt = blockIdx.x;
    const int tid = threadIdx.x;
#pragma unroll
    for (int i = 0; i < 2; ++i) {
        int c = tid + i * 256;
        int lrow = c >> 3, d8 = c & 7;
        *(bf16x8*)&vsh[lrow][d8 * 8] =
            *(const bf16x8*)(qkvb + (size_t)(b * Ls + lt * 64 + lrow) * QKV + 2 * DM + n * DH + d8 * 8);
    }
    __syncthreads();
#pragma unroll
    for (int i = 0; i < 2; ++i) {
        int c = tid + i * 256;
        int d = c >> 3, l8 = c & 7;
        bf16x8 v;
#pragma unroll
        for (int j = 0; j < 8; ++j) v[j] = (short)vsh[l8 * 8 + j][d];
        *(bf16x8*)(vt + ((size_t)(b * NH + n) * DH + d) * Ls + lt * 64 + l8 * 8) = v;
    }
}

// ---------------- flash attention, no-max softmax, exp(pos_bias) in LDS ----------------
// grid (B, NH, L/64); b fastest so 8 batches reuse each ebias tile in L2/L3.
__global__ __launch_bounds__(256) void attn_kernel(const unsigned short* __restrict__ qs,
                                                   const unsigned short* __restrict__ ks,
                                                   const unsigned short* __restrict__ vt,
                                                   const unsigned short* __restrict__ ebb,
                                                   const int* __restrict__ mask,
                                                   unsigned short* __restrict__ ob) {
    __shared__ unsigned short Ksh[64 * 64];
    __shared__ unsigned short Vsh[64 * 64];
    __shared__ unsigned short EBsh[64 * 64];
    __shared__ unsigned short Psh[4][16 * 64];
    __shared__ float maskb[Ls];
    const int b = blockIdx.x, n = blockIdx.y, qt = blockIdx.z;
    const int tid = threadIdx.x, lane = tid & 63, w = tid >> 6;
    const int col = lane & 15, q4 = lane >> 4;
    for (int i = tid; i < Ls; i += 256)
        maskb[i] = (mask[b * Ls + i] > 0) ? 0.0f : -1e30f;
    const unsigned short* qbn = qs + (size_t)(b * NH + n) * Ls * DH;
    const unsigned short* kbn = ks + (size_t)(b * NH + n) * Ls * DH;
    const unsigned short* vbn = vt + (size_t)(b * NH + n) * DH * Ls;
    const unsigned short* ebn = ebb + (size_t)n * Ls * Ls;
    bf16x8 qf[2];
#pragma unroll
    for (int j = 0; j < 2; ++j)
        qf[j] = *(const bf16x8*)(qbn + (size_t)(qt * 64 + w * 16 + col) * DH + q4 * 8 + j * 32);
    const int qrow_c = w * 16 + q4 * 4; // rows owned in C-layout
    float psum[4] = {0.f, 0.f, 0.f, 0.f};
    f32x4 oacc[4];
#pragma unroll
    for (int t = 0; t < 4; ++t) oacc[t] = f32x4{0.f, 0.f, 0.f, 0.f};

    for (int kt = 0; kt < Ls / 64; ++kt) {
        // stage K (64x64), V^T (64x64), EB (64 q-rows x 64 k-cols); source pre-swizzled
#pragma unroll
        for (int i = 0; i < 2; ++i) {
            int c0 = w * 128 + i * 64;
            int p = c0 + lane;
            int row = p >> 3, cin = (p & 7) ^ (row & 7);
            gload_lds16(kbn + (size_t)(kt * 64 + row) * DH + cin * 8, &Ksh[c0 * 8]);
            gload_lds16(vbn + (size_t)row * Ls + kt * 64 + cin * 8, &Vsh[c0 * 8]);
            gload_lds16(ebn + (size_t)(qt * 64 + row) * Ls + kt * 64 + cin * 8, &EBsh[c0 * 8]);
        }
        __syncthreads();
        // S = Q K^T   (scale log2e/8 pre-folded into q)
        f32x4 s[4];
#pragma unroll
        for (int t = 0; t < 4; ++t) {
            s[t] = f32x4{0.f, 0.f, 0.f, 0.f};
            int krow = t * 16 + col;
#pragma unroll
            for (int j = 0; j < 2; ++j) {
                bf16x8 kf = *(const bf16x8*)&Ksh[(krow * 64 + q4 * 8 + j * 32) ^ ((krow & 7) << 3)];
                s[t] = __builtin_amdgcn_mfma_f32_16x16x32_bf16(qf[j], kf, s[t], 0, 0, 0);
            }
        }
        // p = 2^(s + mask) * exp(bias); no max tracking, no per-tile reduces
        float p[4][4];
#pragma unroll
        for (int t = 0; t < 4; ++t) {
            int kg = kt * 64 + t * 16 + col;
            float ma = maskb[kg];
            int chunk = t * 2 + (col >> 3);
#pragma unroll
            for (int r = 0; r < 4; ++r) {
                int rowl = qrow_c + r;
                int bo = rowl * 128 + (((chunk ^ (rowl & 7)) << 4)) + ((col & 7) << 1);
                float ebf = bf2f(*(const unsigned short*)((const char*)EBsh + bo));
                float pv = exp2f(s[t][r] + ma) * ebf;
                p[t][r] = pv;
                psum[r] += pv;
            }
        }
        // P -> LDS (swizzled), then O += P V
        unsigned short* pw = Psh[w];
#pragma unroll
        for (int t = 0; t < 4; ++t)
#pragma unroll
            for (int r = 0; r < 4; ++r) {
                int row = q4 * 4 + r;
                pw[(row * 64 + t * 16 + col) ^ ((row & 7) << 3)] = f2bf(p[t][r]);
            }
#pragma unroll
        for (int ot = 0; ot < 4; ++ot) {
            int vrow = ot * 16 + col;
#pragma unroll
            for (int j = 0; j < 2; ++j) {
                bf16x8 pa = *(const bf16x8*)&pw[(col * 64 + q4 * 8 + j * 32) ^ ((col & 7) << 3)];
                bf16x8 vb = *(const bf16x8*)&Vsh[(vrow * 64 + q4 * 8 + j * 32) ^ ((vrow & 7) << 3)];
                oacc[ot] = __builtin_amdgcn_mfma_f32_16x16x32_bf16(pa, vb, oacc[ot], 0, 0, 0);
            }
        }
        __syncthreads();
    }
    // single deferred row-sum reduce across the 16 lanes of each quarter
#pragma unroll
    for (int r = 0; r < 4; ++r)
#pragma unroll
        for (int msk = 1; msk < 16; msk <<= 1)
            psum[r] += __shfl_xor(psum[r], msk);
    // epilogue: normalize and write o in (B, L, N*D) bf16
#pragma unroll
    for (int r = 0; r < 4; ++r) {
        int lg = qt * 64 + qrow_c + r;
        float inv = 1.0f / psum[r];
#pragma unroll
        for (int ot = 0; ot < 4; ++ot)
            ob[(size_t)(b * Ls + lg) * DM + n * DH + ot * 16 + col] = f2bf(oacc[ot][r] * inv);
    }
}

extern "C" void kernel_launch(void* const* d_in, const int* in_sizes, int n_in,
                              void* d_out, int out_size, void* d_ws, size_t ws_size,
                              hipStream_t stream) {
    const float* x     = (const float*)d_in[0];
    const float* posb  = (const float*)d_in[1];
    const float* qkv_w = (const float*)d_in[2];
    const float* qkv_b = (const float*)d_in[3];
    const float* out_w = (const float*)d_in[4];
    const float* out_b = (const float*)d_in[5];
    const int*   mask  = (const int*)d_in[6];
    float* out = (float*)d_out;

    char* wp = (char*)d_ws;
    auto alloc = [&](size_t bytes) {
        char* p = wp;
        wp += (bytes + 255) & ~(size_t)255;
        return p;
    };
    unsigned short* xb   = (unsigned short*)alloc((size_t)Bb * Ls * DM * 2);
    unsigned short* wqb  = (unsigned short*)alloc((size_t)QKV * DM * 2);
    unsigned short* wob  = (unsigned short*)alloc((size_t)DM * DM * 2);
    unsigned short* ebb  = (unsigned short*)alloc((size_t)NH * Ls * Ls * 2);
    float*          tab  = (float*)alloc((size_t)Ls * DH * 4);
    unsigned short* qkvb = (unsigned short*)alloc((size_t)Bb * Ls * QKV * 2);
    unsigned short* qsb  = (unsigned short*)alloc((size_t)Bb * NH * Ls * DH * 2);
    unsigned short* ksb  = (unsigned short*)alloc((size_t)Bb * NH * Ls * DH * 2);
    unsigned short* vtb  = (unsigned short*)alloc((size_t)Bb * NH * DH * Ls * 2);
    unsigned short* obb  = (unsigned short*)alloc((size_t)Bb * Ls * DM * 2);

    prep_kernel<<<dim3(2048), dim3(256), 0, stream>>>(x, qkv_w, out_w, posb, xb, wqb, wob, ebb, tab);
    gemm_nt<1><<<dim3(64, 18), dim3(256), 0, stream>>>(xb, wqb, qkv_b, (void*)qkvb, Bb * Ls, QKV, DM);
    rope_qk<<<dim3(32, NH, Bb), dim3(256), 0, stream>>>(qkvb, tab, qsb, ksb);
    vtrans<<<dim3(16, NH, Bb), dim3(256), 0, stream>>>(qkvb, vtb);
    attn_kernel<<<dim3(Bb, NH, 16), dim3(256), 0, stream>>>(qsb, ksb, vtb, ebb, mask, obb);
    gemm_nt<0><<<dim3(64, 6), dim3(256), 0, stream>>>(obb, wob, out_b, (void*)out, Bb * Ls, DM, DM);
}

// Round 4
// 285.549 us; speedup vs baseline: 1.0374x; 1.0302x over previous
//
#include <hip/hip_runtime.h>

#define DEVINL __device__ __forceinline__

using bf16x8 = __attribute__((ext_vector_type(8))) short;
using f32x4  = __attribute__((ext_vector_type(4))) float;

constexpr int Bb = 8, Ls = 1024, DM = 768, NH = 12, DH = 64;
constexpr int QKV = 3 * DM; // 2304

DEVINL unsigned short f2bf(float f) {
    union { float f; unsigned u; } v; v.f = f;
    unsigned r = v.u + 0x7FFFu + ((v.u >> 16) & 1u);
    return (unsigned short)(r >> 16);
}
DEVINL float bf2f(unsigned short h) {
    union { unsigned u; float f; } v; v.u = ((unsigned)h) << 16; return v.f;
}

DEVINL void gload_lds16(const void* g, void* l) {
    __builtin_amdgcn_global_load_lds((const __attribute__((address_space(1))) void*)g,
                                     (__attribute__((address_space(3))) void*)l, 16, 0, 0);
}

// ---------------- prep: casts + exp(pos_bias) + rope table ----------------
__global__ void prep_kernel(const float* __restrict__ x, const float* __restrict__ wq,
                            const float* __restrict__ wo, const float* __restrict__ pbias,
                            unsigned short* __restrict__ xb, unsigned short* __restrict__ wqb,
                            unsigned short* __restrict__ wob, unsigned short* __restrict__ ebb,
                            float* __restrict__ tab) {
    const int X4 = Bb * Ls * DM / 4, W4 = QKV * DM / 4, O4 = DM * DM / 4;
    const int E4 = NH * Ls * Ls / 4, TB = Ls * DH;
    const int total = X4 + W4 + O4 + E4 + TB;
    for (int idx = blockIdx.x * blockDim.x + threadIdx.x; idx < total;
         idx += gridDim.x * blockDim.x) {
        if (idx < X4 + W4 + O4) {
            const float4* s; unsigned short* d; int i;
            if (idx < X4)            { s = (const float4*)x;  d = xb;  i = idx; }
            else if (idx < X4 + W4)  { s = (const float4*)wq; d = wqb; i = idx - X4; }
            else                     { s = (const float4*)wo; d = wob; i = idx - X4 - W4; }
            float4 v = s[i];
            ushort4 o;
            o.x = f2bf(v.x); o.y = f2bf(v.y); o.z = f2bf(v.z); o.w = f2bf(v.w);
            ((ushort4*)d)[i] = o;
        } else if (idx < X4 + W4 + O4 + E4) {
            int i = idx - (X4 + W4 + O4);
            float4 v = ((const float4*)pbias)[i];
            ushort4 o;
            o.x = f2bf(__expf(v.x)); o.y = f2bf(__expf(v.y));
            o.z = f2bf(__expf(v.z)); o.w = f2bf(__expf(v.w));
            ((ushort4*)ebb)[i] = o;
        } else {
            int r = idx - (X4 + W4 + O4 + E4);
            int l = r >> 6, c = r & 63, i = c & 31;
            float freq = powf(10000.0f, -(float)i / 32.0f);
            float ang = (float)l * freq;
            tab[l * 64 + c] = (c < 32) ? cosf(ang) : sinf(ang);
        }
    }
}

// ---------------- bf16 NT GEMM: C = A(MxK) * B(NxK)^T + bias ----------------
// 128x128 tile, BK=32, double-buffered LDS, counted-vmcnt pipeline (T3-min),
// sched_barrier(0) pins the MFMA cluster between the barriers (rule #18).
template <int OUT_BF16>
__global__ __launch_bounds__(256) void gemm_nt(const unsigned short* __restrict__ A,
                                               const unsigned short* __restrict__ Bw,
                                               const float* __restrict__ bias,
                                               void* __restrict__ Cout,
                                               int M, int Nn, int K) {
    __shared__ unsigned short As[2][128 * 32];
    __shared__ unsigned short Bs[2][128 * 32];
    const int tid = threadIdx.x, lane = tid & 63, w = tid >> 6;
    const int bm = blockIdx.x * 128, bn = blockIdx.y * 128;
    const int wm = w >> 1, wn = w & 1;
    const int col = lane & 15, q4 = lane >> 4;
    f32x4 acc[4][4] = {};

#define GSTAGE(bi, kt_)                                                              \
    {                                                                                \
        _Pragma("unroll") for (int i = 0; i < 2; ++i) {                              \
            int c0 = w * 128 + i * 64;                                               \
            int p = c0 + lane;                                                       \
            int row = p >> 2;                                                        \
            int kc = (p & 3) ^ (row & 3);                                            \
            gload_lds16(A + (size_t)(bm + row) * K + (kt_)*32 + kc * 8, &As[bi][c0 * 8]); \
            gload_lds16(Bw + (size_t)(bn + row) * K + (kt_)*32 + kc * 8, &Bs[bi][c0 * 8]); \
        }                                                                            \
    }

    const int NT = K / 32;
    GSTAGE(0, 0);
    for (int t = 0; t < NT; ++t) {
        const int cur = t & 1;
        if (t + 1 < NT) {
            GSTAGE(cur ^ 1, t + 1);
            asm volatile("s_waitcnt vmcnt(4)" ::: "memory");
        } else {
            asm volatile("s_waitcnt vmcnt(0)" ::: "memory");
        }
        __builtin_amdgcn_s_barrier();
        asm volatile("" ::: "memory");
        bf16x8 af[4], bfr[4];
#pragma unroll
        for (int tt = 0; tt < 4; ++tt) {
            int ra = wm * 64 + tt * 16 + col;
            int rb = wn * 64 + tt * 16 + col;
            af[tt]  = *(const bf16x8*)&As[cur][(ra * 32 + q4 * 8) ^ ((ra & 3) << 3)];
            bfr[tt] = *(const bf16x8*)&Bs[cur][(rb * 32 + q4 * 8) ^ ((rb & 3) << 3)];
        }
#pragma unroll
        for (int tt = 0; tt < 4; ++tt)
#pragma unroll
            for (int u = 0; u < 4; ++u)
                acc[tt][u] = __builtin_amdgcn_mfma_f32_16x16x32_bf16(af[tt], bfr[u], acc[tt][u], 0, 0, 0);
        __builtin_amdgcn_sched_barrier(0);   // pin MFMAs + their lgkm waits before the barrier
        asm volatile("" ::: "memory");
        __builtin_amdgcn_s_barrier();
    }
#undef GSTAGE
#pragma unroll
    for (int t = 0; t < 4; ++t) {
        int grow_base = bm + wm * 64 + t * 16 + q4 * 4;
#pragma unroll
        for (int u = 0; u < 4; ++u) {
            int gcol = bn + wn * 64 + u * 16 + col;
            float bv = bias[gcol];
#pragma unroll
            for (int r = 0; r < 4; ++r) {
                float vv = acc[t][u][r] + bv;
                if (OUT_BF16)
                    ((unsigned short*)Cout)[(size_t)(grow_base + r) * Nn + gcol] = f2bf(vv);
                else
                    ((float*)Cout)[(size_t)(grow_base + r) * Nn + gcol] = vv;
            }
        }
    }
}

// ---------------- RoPE + repack q,k to (B,N,L,D); q scaled by log2e/8 ----------------
__global__ void rope_qk(const unsigned short* __restrict__ qkvb, const float* __restrict__ tab,
                        unsigned short* __restrict__ qs, unsigned short* __restrict__ ks) {
    const int b = blockIdx.z, n = blockIdx.y;
    const int idx = blockIdx.x * blockDim.x + threadIdx.x; // [0, 8192)
    const int l = idx >> 3, d8 = idx & 7;
    const float QSCL = 0.125f * 1.44269504089f;
    const unsigned short* src = qkvb + (size_t)(b * Ls + l) * QKV + n * DH + d8 * 8;
    float4 cs = *(const float4*)&tab[l * 64 + d8 * 4];
    float4 sn = *(const float4*)&tab[l * 64 + 32 + d8 * 4];
    float cv[4] = {cs.x, cs.y, cs.z, cs.w};
    float sv[4] = {sn.x, sn.y, sn.z, sn.w};
    size_t dsto = ((size_t)(b * NH + n) * Ls + l) * DH + d8 * 8;
    {
        bf16x8 qv = *(const bf16x8*)src;
        bf16x8 ov;
#pragma unroll
        for (int j = 0; j < 4; ++j) {
            float x1 = bf2f((unsigned short)qv[2 * j]), x2 = bf2f((unsigned short)qv[2 * j + 1]);
            ov[2 * j]     = (short)f2bf((x1 * cv[j] - x2 * sv[j]) * QSCL);
            ov[2 * j + 1] = (short)f2bf((x2 * cv[j] + x1 * sv[j]) * QSCL);
        }
        *(bf16x8*)(qs + dsto) = ov;
    }
    {
        bf16x8 kv = *(const bf16x8*)(src + DM);
        bf16x8 ov;
#pragma unroll
        for (int j = 0; j < 4; ++j) {
            float x1 = bf2f((unsigned short)kv[2 * j]), x2 = bf2f((unsigned short)kv[2 * j + 1]);
            ov[2 * j]     = (short)f2bf(x1 * cv[j] - x2 * sv[j]);
            ov[2 * j + 1] = (short)f2bf(x2 * cv[j] + x1 * sv[j]);
        }
        *(bf16x8*)(ks + dsto) = ov;
    }
}

// ---------------- V transpose: (B,L,N,D) slice -> vt (B,N,D,L) ----------------
__global__ void vtrans(const unsigned short* __restrict__ qkvb, unsigned short* __restrict__ vt) {
    __shared__ unsigned short vsh[64][72];
    const int b = blockIdx.z, n = blockIdx.y, lt = blockIdx.x;
    const int tid = threadIdx.x;
#pragma unroll
    for (int i = 0; i < 2; ++i) {
        int c = tid + i * 256;
        int lrow = c >> 3, d8 = c & 7;
        *(bf16x8*)&vsh[lrow][d8 * 8] =
            *(const bf16x8*)(qkvb + (size_t)(b * Ls + lt * 64 + lrow) * QKV + 2 * DM + n * DH + d8 * 8);
    }
    __syncthreads();
#pragma unroll
    for (int i = 0; i < 2; ++i) {
        int c = tid + i * 256;
        int d = c >> 3, l8 = c & 7;
        bf16x8 v;
#pragma unroll
        for (int j = 0; j < 8; ++j) v[j] = (short)vsh[l8 * 8 + j][d];
        *(bf16x8*)(vt + ((size_t)(b * NH + n) * DH + d) * Ls + lt * 64 + l8 * 8) = v;
    }
}

// ---------------- flash attention, no-max softmax, exp(pos_bias) in LDS ----------------
// grid (B, NH, L/64). K/V double-buffered + counted vmcnt; EB and P are
// wave-private (each wave stages/reads its own 16 q-rows) -> no barrier, single buf.
__global__ __launch_bounds__(256) void attn_kernel(const unsigned short* __restrict__ qs,
                                                   const unsigned short* __restrict__ ks,
                                                   const unsigned short* __restrict__ vt,
                                                   const unsigned short* __restrict__ ebb,
                                                   const int* __restrict__ mask,
                                                   unsigned short* __restrict__ ob) {
    __shared__ unsigned short Ksh[2][64 * 64];
    __shared__ unsigned short Vsh[2][64 * 64];
    __shared__ unsigned short EBsh[64 * 64];
    __shared__ unsigned short Psh[4][16 * 64];
    __shared__ float maskb[Ls];
    const int b = blockIdx.x, n = blockIdx.y, qt = blockIdx.z;
    const int tid = threadIdx.x, lane = tid & 63, w = tid >> 6;
    const int col = lane & 15, q4 = lane >> 4;
    for (int i = tid; i < Ls; i += 256)
        maskb[i] = (mask[b * Ls + i] > 0) ? 0.0f : -1e30f;
    const unsigned short* qbn = qs + (size_t)(b * NH + n) * Ls * DH;
    const unsigned short* kbn = ks + (size_t)(b * NH + n) * Ls * DH;
    const unsigned short* vbn = vt + (size_t)(b * NH + n) * DH * Ls;
    const unsigned short* ebn = ebb + (size_t)n * Ls * Ls;
    bf16x8 qf[2];
#pragma unroll
    for (int j = 0; j < 2; ++j)
        qf[j] = *(const bf16x8*)(qbn + (size_t)(qt * 64 + w * 16 + col) * DH + q4 * 8 + j * 32);
    const int qrow_c = w * 16 + q4 * 4; // rows owned in C-layout
    float psum[4] = {0.f, 0.f, 0.f, 0.f};
    f32x4 oacc[4];
#pragma unroll
    for (int t = 0; t < 4; ++t) oacc[t] = f32x4{0.f, 0.f, 0.f, 0.f};
    __syncthreads(); // maskb visible to all waves; drains qf loads too

#define STAGE_KV(bi, kt_)                                                                  \
    {                                                                                      \
        _Pragma("unroll") for (int i = 0; i < 2; ++i) {                                    \
            int c0 = w * 128 + i * 64;                                                     \
            int p = c0 + lane;                                                             \
            int row = p >> 3, cin = (p & 7) ^ (row & 7);                                   \
            gload_lds16(kbn + (size_t)((kt_)*64 + row) * DH + cin * 8, &Ksh[bi][c0 * 8]);  \
            gload_lds16(vbn + (size_t)row * Ls + (kt_)*64 + cin * 8, &Vsh[bi][c0 * 8]);    \
        }                                                                                  \
    }
#define STAGE_EB(kt_)                                                                      \
    {                                                                                      \
        _Pragma("unroll") for (int i = 0; i < 2; ++i) {                                    \
            int c0 = w * 128 + i * 64;                                                     \
            int p = c0 + lane;                                                             \
            int row = p >> 3, cin = (p & 7) ^ (row & 7);                                   \
            gload_lds16(ebn + (size_t)(qt * 64 + row) * Ls + (kt_)*64 + cin * 8, &EBsh[c0 * 8]); \
        }                                                                                  \
    }

    const int NT = Ls / 64;
    STAGE_KV(0, 0);
    STAGE_EB(0);
    for (int kt = 0; kt < NT; ++kt) {
        const int cur = kt & 1;
        if (kt + 1 < NT) {
            STAGE_KV(cur ^ 1, kt + 1);
            asm volatile("s_waitcnt vmcnt(4)" ::: "memory"); // K/V/EB of tile kt landed
        } else {
            asm volatile("s_waitcnt vmcnt(0)" ::: "memory");
        }
        __builtin_amdgcn_s_barrier();
        asm volatile("" ::: "memory");
        // S = Q K^T   (scale log2e/8 pre-folded into q)
        f32x4 s[4];
#pragma unroll
        for (int t = 0; t < 4; ++t) {
            s[t] = f32x4{0.f, 0.f, 0.f, 0.f};
            int krow = t * 16 + col;
#pragma unroll
            for (int j = 0; j < 2; ++j) {
                bf16x8 kf = *(const bf16x8*)&Ksh[cur][(krow * 64 + q4 * 8 + j * 32) ^ ((krow & 7) << 3)];
                s[t] = __builtin_amdgcn_mfma_f32_16x16x32_bf16(qf[j], kf, s[t], 0, 0, 0);
            }
        }
        // p = 2^(s + mask) * exp(bias); no max tracking, no per-tile reduces
        float p[4][4];
#pragma unroll
        for (int t = 0; t < 4; ++t) {
            int kg = kt * 64 + t * 16 + col;
            float ma = maskb[kg];
            int chunk = t * 2 + (col >> 3);
#pragma unroll
            for (int r = 0; r < 4; ++r) {
                int rowl = qrow_c + r;
                int bo = rowl * 128 + (((chunk ^ (rowl & 7)) << 4)) + ((col & 7) << 1);
                float ebf = bf2f(*(const unsigned short*)((const char*)EBsh + bo));
                float pv = exp2f(s[t][r] + ma) * ebf;
                p[t][r] = pv;
                psum[r] += pv;
            }
        }
        // EB consumed (wave-private rows) -> prefetch next EB tile
        asm volatile("s_waitcnt lgkmcnt(0)" ::: "memory");
        __builtin_amdgcn_sched_barrier(0);   // rule #18: nothing crosses the lgkm drain
        if (kt + 1 < NT) STAGE_EB(kt + 1);
        // P -> LDS (wave-private, swizzled), then O += P V
        unsigned short* pw = Psh[w];
#pragma unroll
        for (int t = 0; t < 4; ++t)
#pragma unroll
            for (int r = 0; r < 4; ++r) {
                int row = q4 * 4 + r;
                pw[(row * 64 + t * 16 + col) ^ ((row & 7) << 3)] = f2bf(p[t][r]);
            }
#pragma unroll
        for (int ot = 0; ot < 4; ++ot) {
            int vrow = ot * 16 + col;
#pragma unroll
            for (int j = 0; j < 2; ++j) {
                bf16x8 pa = *(const bf16x8*)&pw[(col * 64 + q4 * 8 + j * 32) ^ ((col & 7) << 3)];
                bf16x8 vb = *(const bf16x8*)&Vsh[cur][(vrow * 64 + q4 * 8 + j * 32) ^ ((vrow & 7) << 3)];
                oacc[ot] = __builtin_amdgcn_mfma_f32_16x16x32_bf16(pa, vb, oacc[ot], 0, 0, 0);
            }
        }
        __builtin_amdgcn_sched_barrier(0);   // pin MFMAs + their lgkm waits before the barrier
        asm volatile("" ::: "memory");
        __builtin_amdgcn_s_barrier();
    }
#undef STAGE_KV
#undef STAGE_EB
    // single deferred row-sum reduce across the 16 lanes of each quarter
#pragma unroll
    for (int r = 0; r < 4; ++r)
#pragma unroll
        for (int msk = 1; msk < 16; msk <<= 1)
            psum[r] += __shfl_xor(psum[r], msk);
    // epilogue: normalize and write o in (B, L, N*D) bf16
#pragma unroll
    for (int r = 0; r < 4; ++r) {
        int lg = qt * 64 + qrow_c + r;
        float inv = 1.0f / psum[r];
#pragma unroll
        for (int ot = 0; ot < 4; ++ot)
            ob[(size_t)(b * Ls + lg) * DM + n * DH + ot * 16 + col] = f2bf(oacc[ot][r] * inv);
    }
}

extern "C" void kernel_launch(void* const* d_in, const int* in_sizes, int n_in,
                              void* d_out, int out_size, void* d_ws, size_t ws_size,
                              hipStream_t stream) {
    const float* x     = (const float*)d_in[0];
    const float* posb  = (const float*)d_in[1];
    const float* qkv_w = (const float*)d_in[2];
    const float* qkv_b = (const float*)d_in[3];
    const float* out_w = (const float*)d_in[4];
    const float* out_b = (const float*)d_in[5];
    const int*   mask  = (const int*)d_in[6];
    float* out = (float*)d_out;

    char* wp = (char*)d_ws;
    auto alloc = [&](size_t bytes) {
        char* p = wp;
        wp += (bytes + 255) & ~(size_t)255;
        return p;
    };
    unsigned short* xb   = (unsigned short*)alloc((size_t)Bb * Ls * DM * 2);
    unsigned short* wqb  = (unsigned short*)alloc((size_t)QKV * DM * 2);
    unsigned short* wob  = (unsigned short*)alloc((size_t)DM * DM * 2);
    unsigned short* ebb  = (unsigned short*)alloc((size_t)NH * Ls * Ls * 2);
    float*          tab  = (float*)alloc((size_t)Ls * DH * 4);
    unsigned short* qkvb = (unsigned short*)alloc((size_t)Bb * Ls * QKV * 2);
    unsigned short* qsb  = (unsigned short*)alloc((size_t)Bb * NH * Ls * DH * 2);
    unsigned short* ksb  = (unsigned short*)alloc((size_t)Bb * NH * Ls * DH * 2);
    unsigned short* vtb  = (unsigned short*)alloc((size_t)Bb * NH * DH * Ls * 2);
    unsigned short* obb  = (unsigned short*)alloc((size_t)Bb * Ls * DM * 2);

    prep_kernel<<<dim3(2048), dim3(256), 0, stream>>>(x, qkv_w, out_w, posb, xb, wqb, wob, ebb, tab);
    gemm_nt<1><<<dim3(64, 18), dim3(256), 0, stream>>>(xb, wqb, qkv_b, (void*)qkvb, Bb * Ls, QKV, DM);
    rope_qk<<<dim3(32, NH, Bb), dim3(256), 0, stream>>>(qkvb, tab, qsb, ksb);
    vtrans<<<dim3(16, NH, Bb), dim3(256), 0, stream>>>(qkvb, vtb);
    attn_kernel<<<dim3(Bb, NH, 16), dim3(256), 0, stream>>>(qsb, ksb, vtb, ebb, mask, obb);
    gemm_nt<0><<<dim3(64, 6), dim3(256), 0, stream>>>(obb, wob, out_b, (void*)out, Bb * Ls, DM, DM);
}

// Round 5
// 277.081 us; speedup vs baseline: 1.0691x; 1.0306x over previous
//
#include <hip/hip_runtime.h>

#define DEVINL __device__ __forceinline__

using bf16x8 = __attribute__((ext_vector_type(8))) short;
using f32x4  = __attribute__((ext_vector_type(4))) float;

constexpr int Bb = 8, Ls = 1024, DM = 768, NH = 12, DH = 64;
constexpr int QKV = 3 * DM; // 2304

DEVINL unsigned short f2bf(float f) {
    union { float f; unsigned u; } v; v.f = f;
    unsigned r = v.u + 0x7FFFu + ((v.u >> 16) & 1u);
    return (unsigned short)(r >> 16);
}
DEVINL float bf2f(unsigned short h) {
    union { unsigned u; float f; } v; v.u = ((unsigned)h) << 16; return v.f;
}

DEVINL void gload_lds16(const void* g, void* l) {
    __builtin_amdgcn_global_load_lds((const __attribute__((address_space(1))) void*)g,
                                     (__attribute__((address_space(3))) void*)l, 16, 0, 0);
}

// ---------------- prep: casts + log2e*pos_bias + rope table ----------------
__global__ void prep_kernel(const float* __restrict__ x, const float* __restrict__ wq,
                            const float* __restrict__ wo, const float* __restrict__ pbias,
                            unsigned short* __restrict__ xb, unsigned short* __restrict__ wqb,
                            unsigned short* __restrict__ wob, unsigned short* __restrict__ ebb,
                            float* __restrict__ tab) {
    const int X4 = Bb * Ls * DM / 4, W4 = QKV * DM / 4, O4 = DM * DM / 4;
    const int E4 = NH * Ls * Ls / 4, TB = Ls * DH;
    const int total = X4 + W4 + O4 + E4 + TB;
    const float L2E = 1.44269504089f;
    for (int idx = blockIdx.x * blockDim.x + threadIdx.x; idx < total;
         idx += gridDim.x * blockDim.x) {
        if (idx < X4 + W4 + O4) {
            const float4* s; unsigned short* d; int i;
            if (idx < X4)            { s = (const float4*)x;  d = xb;  i = idx; }
            else if (idx < X4 + W4)  { s = (const float4*)wq; d = wqb; i = idx - X4; }
            else                     { s = (const float4*)wo; d = wob; i = idx - X4 - W4; }
            float4 v = s[i];
            ushort4 o;
            o.x = f2bf(v.x); o.y = f2bf(v.y); o.z = f2bf(v.z); o.w = f2bf(v.w);
            ((ushort4*)d)[i] = o;
        } else if (idx < X4 + W4 + O4 + E4) {
            int i = idx - (X4 + W4 + O4);
            float4 v = ((const float4*)pbias)[i];
            ushort4 o;
            o.x = f2bf(v.x * L2E); o.y = f2bf(v.y * L2E);
            o.z = f2bf(v.z * L2E); o.w = f2bf(v.w * L2E);
            ((ushort4*)ebb)[i] = o;
        } else {
            int r = idx - (X4 + W4 + O4 + E4);
            int l = r >> 6, c = r & 63, i = c & 31;
            float freq = powf(10000.0f, -(float)i / 32.0f);
            float ang = (float)l * freq;
            tab[l * 64 + c] = (c < 32) ? cosf(ang) : sinf(ang);
        }
    }
}

// ---------------- bf16 NT GEMM: C = A(MxK) * B(NxK)^T + bias ----------------
// 128x128 tile, BK=32, dbuf LDS, counted-vmcnt pipeline, fenced (rule #18).
// 1-D grid, XCD-chunked decode: xcd owns bm-chunk, sweeps bn (B stays in L2).
template <int OUT_BF16>
__global__ __launch_bounds__(256) void gemm_nt(const unsigned short* __restrict__ A,
                                               const unsigned short* __restrict__ Bw,
                                               const float* __restrict__ bias,
                                               void* __restrict__ Cout,
                                               int M, int Nn, int K) {
    __shared__ unsigned short As[2][128 * 32];
    __shared__ unsigned short Bs[2][128 * 32];
    const int tid = threadIdx.x, lane = tid & 63, w = tid >> 6;
    const int f = blockIdx.x;
    const int bm = (8 * (f & 7) + ((f >> 3) & 7)) * 128;  // M/128 == 64 here
    const int bn = (f >> 6) * 128;
    const int wm = w >> 1, wn = w & 1;
    const int col = lane & 15, q4 = lane >> 4;
    f32x4 acc[4][4] = {};

#define GSTAGE(bi, kt_)                                                              \
    {                                                                                \
        _Pragma("unroll") for (int i = 0; i < 2; ++i) {                              \
            int c0 = w * 128 + i * 64;                                               \
            int p = c0 + lane;                                                       \
            int row = p >> 2;                                                        \
            int kc = (p & 3) ^ (row & 3);                                            \
            gload_lds16(A + (size_t)(bm + row) * K + (kt_)*32 + kc * 8, &As[bi][c0 * 8]); \
            gload_lds16(Bw + (size_t)(bn + row) * K + (kt_)*32 + kc * 8, &Bs[bi][c0 * 8]); \
        }                                                                            \
    }

    const int NT = K / 32;
    GSTAGE(0, 0);
    for (int t = 0; t < NT; ++t) {
        const int cur = t & 1;
        if (t + 1 < NT) {
            GSTAGE(cur ^ 1, t + 1);
            asm volatile("s_waitcnt vmcnt(4)" ::: "memory");
        } else {
            asm volatile("s_waitcnt vmcnt(0)" ::: "memory");
        }
        __builtin_amdgcn_s_barrier();
        asm volatile("" ::: "memory");
        bf16x8 af[4], bfr[4];
#pragma unroll
        for (int tt = 0; tt < 4; ++tt) {
            int ra = wm * 64 + tt * 16 + col;
            int rb = wn * 64 + tt * 16 + col;
            af[tt]  = *(const bf16x8*)&As[cur][(ra * 32 + q4 * 8) ^ ((ra & 3) << 3)];
            bfr[tt] = *(const bf16x8*)&Bs[cur][(rb * 32 + q4 * 8) ^ ((rb & 3) << 3)];
        }
#pragma unroll
        for (int tt = 0; tt < 4; ++tt)
#pragma unroll
            for (int u = 0; u < 4; ++u)
                acc[tt][u] = __builtin_amdgcn_mfma_f32_16x16x32_bf16(af[tt], bfr[u], acc[tt][u], 0, 0, 0);
        __builtin_amdgcn_sched_barrier(0);
        asm volatile("" ::: "memory");
        __builtin_amdgcn_s_barrier();
    }
#undef GSTAGE
#pragma unroll
    for (int t = 0; t < 4; ++t) {
        int grow_base = bm + wm * 64 + t * 16 + q4 * 4;
#pragma unroll
        for (int u = 0; u < 4; ++u) {
            int gcol = bn + wn * 64 + u * 16 + col;
            float bv = bias[gcol];
#pragma unroll
            for (int r = 0; r < 4; ++r) {
                float vv = acc[t][u][r] + bv;
                if (OUT_BF16)
                    ((unsigned short*)Cout)[(size_t)(grow_base + r) * Nn + gcol] = f2bf(vv);
                else
                    ((float*)Cout)[(size_t)(grow_base + r) * Nn + gcol] = vv;
            }
        }
    }
}

// ---------------- RoPE (q,k) + V transpose, merged; q scaled log2e/8 ----------------
__global__ void ropev_kernel(const unsigned short* __restrict__ qkvb, const float* __restrict__ tab,
                             unsigned short* __restrict__ qs, unsigned short* __restrict__ ks,
                             unsigned short* __restrict__ vt) {
    __shared__ unsigned short vsh[64][72];
    const int b = blockIdx.z, n = blockIdx.y, lt = blockIdx.x;
    const int tid = threadIdx.x;
    const float QSCL = 0.125f * 1.44269504089f;
    // ---- RoPE on q,k for 64 l-rows ----
#pragma unroll
    for (int i = 0; i < 2; ++i) {
        int idx = tid + i * 256;                 // [0,512)
        int l = lt * 64 + (idx >> 3), d8 = idx & 7;
        const unsigned short* src = qkvb + (size_t)(b * Ls + l) * QKV + n * DH + d8 * 8;
        float4 cs = *(const float4*)&tab[l * 64 + d8 * 4];
        float4 sn = *(const float4*)&tab[l * 64 + 32 + d8 * 4];
        float cv[4] = {cs.x, cs.y, cs.z, cs.w};
        float sv[4] = {sn.x, sn.y, sn.z, sn.w};
        size_t dsto = ((size_t)(b * NH + n) * Ls + l) * DH + d8 * 8;
        {
            bf16x8 qv = *(const bf16x8*)src;
            bf16x8 ov;
#pragma unroll
            for (int j = 0; j < 4; ++j) {
                float x1 = bf2f((unsigned short)qv[2 * j]), x2 = bf2f((unsigned short)qv[2 * j + 1]);
                ov[2 * j]     = (short)f2bf((x1 * cv[j] - x2 * sv[j]) * QSCL);
                ov[2 * j + 1] = (short)f2bf((x2 * cv[j] + x1 * sv[j]) * QSCL);
            }
            *(bf16x8*)(qs + dsto) = ov;
        }
        {
            bf16x8 kv = *(const bf16x8*)(src + DM);
            bf16x8 ov;
#pragma unroll
            for (int j = 0; j < 4; ++j) {
                float x1 = bf2f((unsigned short)kv[2 * j]), x2 = bf2f((unsigned short)kv[2 * j + 1]);
                ov[2 * j]     = (short)f2bf(x1 * cv[j] - x2 * sv[j]);
                ov[2 * j + 1] = (short)f2bf(x2 * cv[j] + x1 * sv[j]);
            }
            *(bf16x8*)(ks + dsto) = ov;
        }
    }
    // ---- V transpose for the same 64 l-rows ----
#pragma unroll
    for (int i = 0; i < 2; ++i) {
        int c = tid + i * 256;
        int lrow = c >> 3, d8 = c & 7;
        *(bf16x8*)&vsh[lrow][d8 * 8] =
            *(const bf16x8*)(qkvb + (size_t)(b * Ls + lt * 64 + lrow) * QKV + 2 * DM + n * DH + d8 * 8);
    }
    __syncthreads();
#pragma unroll
    for (int i = 0; i < 2; ++i) {
        int c = tid + i * 256;
        int d = c >> 3, l8 = c & 7;
        bf16x8 v;
#pragma unroll
        for (int j = 0; j < 8; ++j) v[j] = (short)vsh[l8 * 8 + j][d];
        *(bf16x8*)(vt + ((size_t)(b * NH + n) * DH + d) * Ls + lt * 64 + l8 * 8) = v;
    }
}

// ---------------- flash attention, swapped-operand S^T, EB+mask as MFMA C ----------------
// 1-D grid 1536, decode f = b*192 + t (t = n + 12*qt): same-EB blocks share an XCD.
__global__ __launch_bounds__(256) void attn_kernel(const unsigned short* __restrict__ qs,
                                                   const unsigned short* __restrict__ ks,
                                                   const unsigned short* __restrict__ vt,
                                                   const unsigned short* __restrict__ ebb,
                                                   const int* __restrict__ mask,
                                                   unsigned short* __restrict__ ob) {
    __shared__ unsigned short Ksh[2][64 * 64];
    __shared__ unsigned short Vsh[2][64 * 64];
    __shared__ unsigned short EBsh[64 * 64];
    __shared__ unsigned short Psh[4][16 * 64];
    __shared__ float maskb[Ls];
    const int f = blockIdx.x;
    const int b = f / 192, t192 = f % 192;
    const int n = t192 % 12, qt = t192 / 12;
    const int tid = threadIdx.x, lane = tid & 63, w = tid >> 6;
    const int col = lane & 15, q4 = lane >> 4;
    for (int i = tid; i < Ls; i += 256)
        maskb[i] = (mask[b * Ls + i] > 0) ? 0.0f : -1e30f;
    const unsigned short* qbn = qs + (size_t)(b * NH + n) * Ls * DH;
    const unsigned short* kbn = ks + (size_t)(b * NH + n) * Ls * DH;
    const unsigned short* vbn = vt + (size_t)(b * NH + n) * DH * Ls;
    const unsigned short* ebn = ebb + (size_t)n * Ls * Ls;
    bf16x8 qf[2];
#pragma unroll
    for (int j = 0; j < 2; ++j)
        qf[j] = *(const bf16x8*)(qbn + (size_t)(qt * 64 + w * 16 + col) * DH + q4 * 8 + j * 32);
    float psum = 0.f;            // lane owns q = w*16+col
    f32x4 oacc[4];
#pragma unroll
    for (int t = 0; t < 4; ++t) oacc[t] = f32x4{0.f, 0.f, 0.f, 0.f};
    __syncthreads(); // maskb visible to all waves

#define STAGE_KV(bi, kt_)                                                                  \
    {                                                                                      \
        _Pragma("unroll") for (int i = 0; i < 2; ++i) {                                    \
            int c0 = w * 128 + i * 64;                                                     \
            int p = c0 + lane;                                                             \
            int row = p >> 3, cin = (p & 7) ^ (row & 7);                                   \
            gload_lds16(kbn + (size_t)((kt_)*64 + row) * DH + cin * 8, &Ksh[bi][c0 * 8]);  \
            gload_lds16(vbn + (size_t)row * Ls + (kt_)*64 + cin * 8, &Vsh[bi][c0 * 8]);    \
        }                                                                                  \
    }
#define STAGE_EB(kt_)                                                                      \
    {                                                                                      \
        _Pragma("unroll") for (int i = 0; i < 2; ++i) {                                    \
            int c0 = w * 128 + i * 64;                                                     \
            int p = c0 + lane;                                                             \
            int row = p >> 3, cin = (p & 7) ^ (row & 7);                                   \
            gload_lds16(ebn + (size_t)(qt * 64 + row) * Ls + (kt_)*64 + cin * 8, &EBsh[c0 * 8]); \
        }                                                                                  \
    }

    const int NT = Ls / 64;
    STAGE_KV(0, 0);
    STAGE_EB(0);
    for (int kt = 0; kt < NT; ++kt) {
        const int cur = kt & 1;
        if (kt + 1 < NT) {
            STAGE_KV(cur ^ 1, kt + 1);
            asm volatile("s_waitcnt vmcnt(4)" ::: "memory"); // K/V/EB of tile kt landed
        } else {
            asm volatile("s_waitcnt vmcnt(0)" ::: "memory");
        }
        __builtin_amdgcn_s_barrier();
        asm volatile("" ::: "memory");
        // C-init: s^T[k][q] starts at log2e*bias + mask (lane: q=w*16+col, k=t*16+q4*4+r)
        f32x4 s[4];
#pragma unroll
        for (int t = 0; t < 4; ++t) {
            const f32x4 ma = *(const f32x4*)&maskb[kt * 64 + t * 16 + q4 * 4];
            ushort4 ebv = *(const ushort4*)&EBsh[(w * 16 + col) * 64 +
                                                (((t * 16 + q4 * 4)) ^ ((col & 7) << 3))];
            s[t][0] = bf2f(ebv.x) + ma[0];
            s[t][1] = bf2f(ebv.y) + ma[1];
            s[t][2] = bf2f(ebv.z) + ma[2];
            s[t][3] = bf2f(ebv.w) + ma[3];
        }
        // S^T = K Q^T (+C): A = K-frag, B = Q-frag
        __builtin_amdgcn_s_setprio(1);
#pragma unroll
        for (int t = 0; t < 4; ++t) {
            int krow = t * 16 + col;
#pragma unroll
            for (int j = 0; j < 2; ++j) {
                bf16x8 kf = *(const bf16x8*)&Ksh[cur][(krow * 64 + q4 * 8 + j * 32) ^ ((krow & 7) << 3)];
                s[t] = __builtin_amdgcn_mfma_f32_16x16x32_bf16(kf, qf[j], s[t], 0, 0, 0);
            }
        }
        __builtin_amdgcn_s_setprio(0);
        // p = 2^s; per-lane scalar psum (single q-row per lane)
        float p[4][4];
#pragma unroll
        for (int t = 0; t < 4; ++t)
#pragma unroll
            for (int r = 0; r < 4; ++r) {
                float pv = exp2f(s[t][r]);
                p[t][r] = pv;
                psum += pv;
            }
        // EB consumed -> drain LDS queue, prefetch next EB tile
        asm volatile("s_waitcnt lgkmcnt(0)" ::: "memory");
        __builtin_amdgcn_sched_barrier(0);
        if (kt + 1 < NT) STAGE_EB(kt + 1);
        // P^T pack: 4 consecutive k per lane -> cvt_pk pairs, b64 writes into [16 q][64 k]
        unsigned short* pw = Psh[w];
#pragma unroll
        for (int t = 0; t < 4; ++t) {
            unsigned pk0, pk1;
            asm("v_cvt_pk_bf16_f32 %0, %1, %2" : "=v"(pk0) : "v"(p[t][0]), "v"(p[t][1]));
            asm("v_cvt_pk_bf16_f32 %0, %1, %2" : "=v"(pk1) : "v"(p[t][2]), "v"(p[t][3]));
            uint2 pk; pk.x = pk0; pk.y = pk1;
            *(uint2*)&pw[(col * 64) + (((t * 16 + q4 * 4)) ^ ((col & 7) << 3))] = pk;
        }
        // O += P V : A-frags (2, hoisted) from P rows q=col; B from V^T
        bf16x8 pa[2];
#pragma unroll
        for (int ksl = 0; ksl < 2; ++ksl)
            pa[ksl] = *(const bf16x8*)&pw[(col * 64) + ((ksl * 32 + q4 * 8) ^ ((col & 7) << 3))];
        __builtin_amdgcn_s_setprio(1);
#pragma unroll
        for (int ot = 0; ot < 4; ++ot) {
            int vrow = ot * 16 + col;
#pragma unroll
            for (int ksl = 0; ksl < 2; ++ksl) {
                bf16x8 vb = *(const bf16x8*)&Vsh[cur][(vrow * 64 + q4 * 8 + ksl * 32) ^ ((vrow & 7) << 3)];
                oacc[ot] = __builtin_amdgcn_mfma_f32_16x16x32_bf16(pa[ksl], vb, oacc[ot], 0, 0, 0);
            }
        }
        __builtin_amdgcn_s_setprio(0);
        __builtin_amdgcn_sched_barrier(0);   // pin cluster + its lgkm waits before the barrier
        asm volatile("" ::: "memory");
        __builtin_amdgcn_s_barrier();
    }
#undef STAGE_KV
#undef STAGE_EB
    // psum: reduce the 4 q4-copies of each q-col, then redistribute to C-layout rows
    psum += __shfl_xor(psum, 16);
    psum += __shfl_xor(psum, 32);
    float inv[4];
#pragma unroll
    for (int r = 0; r < 4; ++r)
        inv[r] = 1.0f / __shfl(psum, q4 * 4 + r);
    // epilogue: normalize and write o in (B, L, N*D) bf16
#pragma unroll
    for (int r = 0; r < 4; ++r) {
        int lg = qt * 64 + w * 16 + q4 * 4 + r;
#pragma unroll
        for (int ot = 0; ot < 4; ++ot)
            ob[(size_t)(b * Ls + lg) * DM + n * DH + ot * 16 + col] = f2bf(oacc[ot][r] * inv[r]);
    }
}

extern "C" void kernel_launch(void* const* d_in, const int* in_sizes, int n_in,
                              void* d_out, int out_size, void* d_ws, size_t ws_size,
                              hipStream_t stream) {
    const float* x     = (const float*)d_in[0];
    const float* posb  = (const float*)d_in[1];
    const float* qkv_w = (const float*)d_in[2];
    const float* qkv_b = (const float*)d_in[3];
    const float* out_w = (const float*)d_in[4];
    const float* out_b = (const float*)d_in[5];
    const int*   mask  = (const int*)d_in[6];
    float* out = (float*)d_out;

    char* wp = (char*)d_ws;
    auto alloc = [&](size_t bytes) {
        char* p = wp;
        wp += (bytes + 255) & ~(size_t)255;
        return p;
    };
    unsigned short* xb   = (unsigned short*)alloc((size_t)Bb * Ls * DM * 2);
    unsigned short* wqb  = (unsigned short*)alloc((size_t)QKV * DM * 2);
    unsigned short* wob  = (unsigned short*)alloc((size_t)DM * DM * 2);
    unsigned short* ebb  = (unsigned short*)alloc((size_t)NH * Ls * Ls * 2);
    float*          tab  = (float*)alloc((size_t)Ls * DH * 4);
    unsigned short* qkvb = (unsigned short*)alloc((size_t)Bb * Ls * QKV * 2);
    unsigned short* qsb  = (unsigned short*)alloc((size_t)Bb * NH * Ls * DH * 2);
    unsigned short* ksb  = (unsigned short*)alloc((size_t)Bb * NH * Ls * DH * 2);
    unsigned short* vtb  = (unsigned short*)alloc((size_t)Bb * NH * DH * Ls * 2);
    unsigned short* obb  = (unsigned short*)alloc((size_t)Bb * Ls * DM * 2);

    prep_kernel<<<dim3(2048), dim3(256), 0, stream>>>(x, qkv_w, out_w, posb, xb, wqb, wob, ebb, tab);
    gemm_nt<1><<<dim3(1152), dim3(256), 0, stream>>>(xb, wqb, qkv_b, (void*)qkvb, Bb * Ls, QKV, DM);
    ropev_kernel<<<dim3(16, NH, Bb), dim3(256), 0, stream>>>(qkvb, tab, qsb, ksb, vtb);
    attn_kernel<<<dim3(1536), dim3(256), 0, stream>>>(qsb, ksb, vtb, ebb, mask, obb);
    gemm_nt<0><<<dim3(384), dim3(256), 0, stream>>>(obb, wob, out_b, (void*)out, Bb * Ls, DM, DM);
}

// Round 6
// 268.681 us; speedup vs baseline: 1.1025x; 1.0313x over previous
//
#include <hip/hip_runtime.h>

#define DEVINL __device__ __forceinline__

using bf16x8 = __attribute__((ext_vector_type(8))) short;
using f32x4  = __attribute__((ext_vector_type(4))) float;

constexpr int Bb = 8, Ls = 1024, DM = 768, NH = 12, DH = 64;
constexpr int QKV = 3 * DM; // 2304

DEVINL unsigned short f2bf(float f) {
    union { float f; unsigned u; } v; v.f = f;
    unsigned r = v.u + 0x7FFFu + ((v.u >> 16) & 1u);
    return (unsigned short)(r >> 16);
}
DEVINL float bf2f(unsigned short h) {
    union { unsigned u; float f; } v; v.u = ((unsigned)h) << 16; return v.f;
}

DEVINL void gload_lds16(const void* g, void* l) {
    __builtin_amdgcn_global_load_lds((const __attribute__((address_space(1))) void*)g,
                                     (__attribute__((address_space(3))) void*)l, 16, 0, 0);
}

// ---------------- prep: casts + log2e*pos_bias + interleaved (cos,sin) rope table ----------------
__global__ void prep_kernel(const float* __restrict__ x, const float* __restrict__ wq,
                            const float* __restrict__ wo, const float* __restrict__ pbias,
                            unsigned short* __restrict__ xb, unsigned short* __restrict__ wqb,
                            unsigned short* __restrict__ wob, unsigned short* __restrict__ ebb,
                            float* __restrict__ tab) {
    const int X4 = Bb * Ls * DM / 4, W4 = QKV * DM / 4, O4 = DM * DM / 4;
    const int E4 = NH * Ls * Ls / 4, TB = Ls * DH;
    const int total = X4 + W4 + O4 + E4 + TB;
    const float L2E = 1.44269504089f;
    for (int idx = blockIdx.x * blockDim.x + threadIdx.x; idx < total;
         idx += gridDim.x * blockDim.x) {
        if (idx < X4 + W4 + O4) {
            const float4* s; unsigned short* d; int i;
            if (idx < X4)            { s = (const float4*)x;  d = xb;  i = idx; }
            else if (idx < X4 + W4)  { s = (const float4*)wq; d = wqb; i = idx - X4; }
            else                     { s = (const float4*)wo; d = wob; i = idx - X4 - W4; }
            float4 v = s[i];
            ushort4 o;
            o.x = f2bf(v.x); o.y = f2bf(v.y); o.z = f2bf(v.z); o.w = f2bf(v.w);
            ((ushort4*)d)[i] = o;
        } else if (idx < X4 + W4 + O4 + E4) {
            int i = idx - (X4 + W4 + O4);
            float4 v = ((const float4*)pbias)[i];
            ushort4 o;
            o.x = f2bf(v.x * L2E); o.y = f2bf(v.y * L2E);
            o.z = f2bf(v.z * L2E); o.w = f2bf(v.w * L2E);
            ((ushort4*)ebb)[i] = o;
        } else {
            int r = idx - (X4 + W4 + O4 + E4);
            int l = r >> 6, c = r & 63, i = c >> 1;     // pair index; interleaved cos/sin
            float freq = powf(10000.0f, -(float)i / 32.0f);
            float ang = (float)l * freq;
            tab[l * 64 + c] = (c & 1) ? sinf(ang) : cosf(ang);
        }
    }
}

// ---------------- fused QKV GEMM^T + RoPE + V-transpose ----------------
// C = W(2304x768) * X^T(8192x768)^T -> C[qkvdim][token]; lanes own 4 consecutive
// qkv-dims so RoPE pairs are lane-local. Epilogue transposes the wave's 64x64
// tile through wave-private LDS (XOR-swizzled) for coalesced stores into
// qs/ks (B,N,L,D) and vt (B,N,D,L). grid 1152: bm fast (18), bn slow (64).
__global__ __launch_bounds__(256) void gemm_qkv(const unsigned short* __restrict__ A,
                                                const unsigned short* __restrict__ Bw,
                                                const float* __restrict__ bias,
                                                const float* __restrict__ tab,
                                                unsigned short* __restrict__ qs,
                                                unsigned short* __restrict__ ks,
                                                unsigned short* __restrict__ vt) {
    constexpr int K = 768;
    __shared__ unsigned short Sh[16384];              // [As dbuf | Bs dbuf], 32KB
#define ASP(bi) (Sh + (bi)*4096)
#define BSP(bi) (Sh + 8192 + (bi)*4096)
    const int tid = threadIdx.x, lane = tid & 63, w = tid >> 6;
    const int f = blockIdx.x;
    const int bm = (f % 18) * 128, bn = (f / 18) * 128;
    const int wm = w >> 1, wn = w & 1;
    const int col = lane & 15, q4 = lane >> 4;
    f32x4 acc[4][4] = {};

#define GSTAGE(bi, kt_)                                                                   \
    {                                                                                     \
        _Pragma("unroll") for (int i = 0; i < 2; ++i) {                                   \
            int c0 = w * 128 + i * 64;                                                    \
            int p = c0 + lane;                                                            \
            int row = p >> 2;                                                             \
            int kc = (p & 3) ^ (row & 3);                                                 \
            gload_lds16(A + (size_t)(bm + row) * K + (kt_)*32 + kc * 8, ASP(bi) + c0 * 8);  \
            gload_lds16(Bw + (size_t)(bn + row) * K + (kt_)*32 + kc * 8, BSP(bi) + c0 * 8); \
        }                                                                                 \
    }

    const int NT = K / 32;
    GSTAGE(0, 0);
    for (int t = 0; t < NT; ++t) {
        const int cur = t & 1;
        if (t + 1 < NT) {
            GSTAGE(cur ^ 1, t + 1);
            asm volatile("s_waitcnt vmcnt(4)" ::: "memory");
        } else {
            asm volatile("s_waitcnt vmcnt(0)" ::: "memory");
        }
        __builtin_amdgcn_s_barrier();
        asm volatile("" ::: "memory");
        bf16x8 af[4], bfr[4];
#pragma unroll
        for (int tt = 0; tt < 4; ++tt) {
            int ra = wm * 64 + tt * 16 + col;
            int rb = wn * 64 + tt * 16 + col;
            af[tt]  = *(const bf16x8*)&ASP(cur)[(ra * 32 + q4 * 8) ^ ((ra & 3) << 3)];
            bfr[tt] = *(const bf16x8*)&BSP(cur)[(rb * 32 + q4 * 8) ^ ((rb & 3) << 3)];
        }
#pragma unroll
        for (int tt = 0; tt < 4; ++tt)
#pragma unroll
            for (int u = 0; u < 4; ++u)
                acc[tt][u] = __builtin_amdgcn_mfma_f32_16x16x32_bf16(af[tt], bfr[u], acc[tt][u], 0, 0, 0);
        __builtin_amdgcn_sched_barrier(0);
        asm volatile("" ::: "memory");
        __builtin_amdgcn_s_barrier();
    }
#undef GSTAGE
    // ---- epilogue: bias + rope (f32, lane-local pairs) -> LDS transpose -> stores ----
    __syncthreads();                                   // all waves done reading Sh
    unsigned short* tr = Sh + w * 4096;                // wave-private 64x64 bf16
    const int btype = bm / 768;                        // 0=q 1=k 2=v (tiles align)
    const int n = ((bm % 768) + wm * 64) >> 6;
    const float QS = (btype == 0) ? 0.125f * 1.44269504089f : 1.0f;
#pragma unroll
    for (int t = 0; t < 4; ++t) {
        const int dloc = t * 16 + q4 * 4;
        const int grow = bm + wm * 64 + dloc;
        float bv[4];
#pragma unroll
        for (int r = 0; r < 4; ++r) bv[r] = bias[grow + r];
#pragma unroll
        for (int u = 0; u < 4; ++u) {
            const int lt_ = u * 16 + col;
            if (btype < 2) {
                const int l = (bn + wn * 64 + lt_) & 1023;
                float4 cs = *(const float4*)&tab[l * 64 + dloc]; // c_i,s_i,c_{i+1},s_{i+1}
                float x0 = acc[t][u][0] + bv[0], x1 = acc[t][u][1] + bv[1];
                float x2 = acc[t][u][2] + bv[2], x3 = acc[t][u][3] + bv[3];
                ushort4 pk;
                pk.x = f2bf((x0 * cs.x - x1 * cs.y) * QS);
                pk.y = f2bf((x1 * cs.x + x0 * cs.y) * QS);
                pk.z = f2bf((x2 * cs.z - x3 * cs.w) * QS);
                pk.w = f2bf((x3 * cs.z + x2 * cs.w) * QS);
                *(ushort4*)&tr[lt_ * 64 + (dloc ^ ((lt_ & 7) << 3))] = pk;   // [tok][d]
            } else {
#pragma unroll
                for (int r = 0; r < 4; ++r) {
                    int dr = dloc + r;
                    tr[dr * 64 + (lt_ ^ ((dr & 7) << 3))] = f2bf(acc[t][u][r] + bv[r]); // [d][tok]
                }
            }
        }
    }
    asm volatile("s_waitcnt lgkmcnt(0)" ::: "memory");
    __builtin_amdgcn_sched_barrier(0);
    const int gt0 = bn + wn * 64;                      // 64 tokens, same batch
    const int b2 = gt0 >> 10;
    if (btype < 2) {
        const int l2 = (gt0 + lane) & 1023;
        unsigned short* dstp = (btype ? ks : qs) + ((size_t)(b2 * NH + n) * Ls + l2) * DH;
#pragma unroll
        for (int c8 = 0; c8 < 8; ++c8)
            *(bf16x8*)&dstp[c8 * 8] =
                *(const bf16x8*)&tr[lane * 64 + ((c8 * 8) ^ ((lane & 7) << 3))];
    } else {
        unsigned short* dstp = vt + ((size_t)(b2 * NH + n) * DH + lane) * Ls + (gt0 & 1023);
#pragma unroll
        for (int c8 = 0; c8 < 8; ++c8)
            *(bf16x8*)&dstp[c8 * 8] =
                *(const bf16x8*)&tr[lane * 64 + ((c8 * 8) ^ ((lane & 7) << 3))];
    }
#undef ASP
#undef BSP
}

// ---------------- bf16 NT GEMM (out-proj): C = A(MxK) * B(NxK)^T + bias, f32 out ----------------
template <int OUT_BF16>
__global__ __launch_bounds__(256) void gemm_nt(const unsigned short* __restrict__ A,
                                               const unsigned short* __restrict__ Bw,
                                               const float* __restrict__ bias,
                                               void* __restrict__ Cout,
                                               int M, int Nn, int K) {
    __shared__ unsigned short As[2][128 * 32];
    __shared__ unsigned short Bs[2][128 * 32];
    const int tid = threadIdx.x, lane = tid & 63, w = tid >> 6;
    const int f = blockIdx.x;
    const int bm = (8 * (f & 7) + ((f >> 3) & 7)) * 128;  // M/128 == 64 here
    const int bn = (f >> 6) * 128;
    const int wm = w >> 1, wn = w & 1;
    const int col = lane & 15, q4 = lane >> 4;
    f32x4 acc[4][4] = {};

#define GSTAGE(bi, kt_)                                                              \
    {                                                                                \
        _Pragma("unroll") for (int i = 0; i < 2; ++i) {                              \
            int c0 = w * 128 + i * 64;                                               \
            int p = c0 + lane;                                                       \
            int row = p >> 2;                                                        \
            int kc = (p & 3) ^ (row & 3);                                            \
            gload_lds16(A + (size_t)(bm + row) * K + (kt_)*32 + kc * 8, &As[bi][c0 * 8]); \
            gload_lds16(Bw + (size_t)(bn + row) * K + (kt_)*32 + kc * 8, &Bs[bi][c0 * 8]); \
        }                                                                            \
    }

    const int NT = K / 32;
    GSTAGE(0, 0);
    for (int t = 0; t < NT; ++t) {
        const int cur = t & 1;
        if (t + 1 < NT) {
            GSTAGE(cur ^ 1, t + 1);
            asm volatile("s_waitcnt vmcnt(4)" ::: "memory");
        } else {
            asm volatile("s_waitcnt vmcnt(0)" ::: "memory");
        }
        __builtin_amdgcn_s_barrier();
        asm volatile("" ::: "memory");
        bf16x8 af[4], bfr[4];
#pragma unroll
        for (int tt = 0; tt < 4; ++tt) {
            int ra = wm * 64 + tt * 16 + col;
            int rb = wn * 64 + tt * 16 + col;
            af[tt]  = *(const bf16x8*)&As[cur][(ra * 32 + q4 * 8) ^ ((ra & 3) << 3)];
            bfr[tt] = *(const bf16x8*)&Bs[cur][(rb * 32 + q4 * 8) ^ ((rb & 3) << 3)];
        }
#pragma unroll
        for (int tt = 0; tt < 4; ++tt)
#pragma unroll
            for (int u = 0; u < 4; ++u)
                acc[tt][u] = __builtin_amdgcn_mfma_f32_16x16x32_bf16(af[tt], bfr[u], acc[tt][u], 0, 0, 0);
        __builtin_amdgcn_sched_barrier(0);
        asm volatile("" ::: "memory");
        __builtin_amdgcn_s_barrier();
    }
#undef GSTAGE
#pragma unroll
    for (int t = 0; t < 4; ++t) {
        int grow_base = bm + wm * 64 + t * 16 + q4 * 4;
#pragma unroll
        for (int u = 0; u < 4; ++u) {
            int gcol = bn + wn * 64 + u * 16 + col;
            float bv = bias[gcol];
#pragma unroll
            for (int r = 0; r < 4; ++r) {
                float vv = acc[t][u][r] + bv;
                if (OUT_BF16)
                    ((unsigned short*)Cout)[(size_t)(grow_base + r) * Nn + gcol] = f2bf(vv);
                else
                    ((float*)Cout)[(size_t)(grow_base + r) * Nn + gcol] = vv;
            }
        }
    }
}

// ---------------- flash attention, swapped-operand S^T, EB+mask as MFMA C ----------------
// 1-D grid 1536, decode f = b*192 + t (t = n + 12*qt): same-EB blocks share an XCD.
__global__ __launch_bounds__(256) void attn_kernel(const unsigned short* __restrict__ qs,
                                                   const unsigned short* __restrict__ ks,
                                                   const unsigned short* __restrict__ vt,
                                                   const unsigned short* __restrict__ ebb,
                                                   const int* __restrict__ mask,
                                                   unsigned short* __restrict__ ob) {
    __shared__ unsigned short Ksh[2][64 * 64];
    __shared__ unsigned short Vsh[2][64 * 64];
    __shared__ unsigned short EBsh[64 * 64];
    __shared__ unsigned short Psh[4][16 * 64];
    __shared__ float maskb[Ls];
    const int f = blockIdx.x;
    const int b = f / 192, t192 = f % 192;
    const int n = t192 % 12, qt = t192 / 12;
    const int tid = threadIdx.x, lane = tid & 63, w = tid >> 6;
    const int col = lane & 15, q4 = lane >> 4;
    for (int i = tid; i < Ls; i += 256)
        maskb[i] = (mask[b * Ls + i] > 0) ? 0.0f : -1e30f;
    const unsigned short* qbn = qs + (size_t)(b * NH + n) * Ls * DH;
    const unsigned short* kbn = ks + (size_t)(b * NH + n) * Ls * DH;
    const unsigned short* vbn = vt + (size_t)(b * NH + n) * DH * Ls;
    const unsigned short* ebn = ebb + (size_t)n * Ls * Ls;
    bf16x8 qf[2];
#pragma unroll
    for (int j = 0; j < 2; ++j)
        qf[j] = *(const bf16x8*)(qbn + (size_t)(qt * 64 + w * 16 + col) * DH + q4 * 8 + j * 32);
    float psum = 0.f;            // lane owns q = w*16+col
    f32x4 oacc[4];
#pragma unroll
    for (int t = 0; t < 4; ++t) oacc[t] = f32x4{0.f, 0.f, 0.f, 0.f};
    __syncthreads(); // maskb visible to all waves

#define STAGE_KV(bi, kt_)                                                                  \
    {                                                                                      \
        _Pragma("unroll") for (int i = 0; i < 2; ++i) {                                    \
            int c0 = w * 128 + i * 64;                                                     \
            int p = c0 + lane;                                                             \
            int row = p >> 3, cin = (p & 7) ^ (row & 7);                                   \
            gload_lds16(kbn + (size_t)((kt_)*64 + row) * DH + cin * 8, &Ksh[bi][c0 * 8]);  \
            gload_lds16(vbn + (size_t)row * Ls + (kt_)*64 + cin * 8, &Vsh[bi][c0 * 8]);    \
        }                                                                                  \
    }
#define STAGE_EB(kt_)                                                                      \
    {                                                                                      \
        _Pragma("unroll") for (int i = 0; i < 2; ++i) {                                    \
            int c0 = w * 128 + i * 64;                                                     \
            int p = c0 + lane;                                                             \
            int row = p >> 3, cin = (p & 7) ^ (row & 7);                                   \
            gload_lds16(ebn + (size_t)(qt * 64 + row) * Ls + (kt_)*64 + cin * 8, &EBsh[c0 * 8]); \
        }                                                                                  \
    }

    const int NT = Ls / 64;
    STAGE_KV(0, 0);
    STAGE_EB(0);
    for (int kt = 0; kt < NT; ++kt) {
        const int cur = kt & 1;
        if (kt + 1 < NT) {
            STAGE_KV(cur ^ 1, kt + 1);
            asm volatile("s_waitcnt vmcnt(4)" ::: "memory"); // K/V/EB of tile kt landed
        } else {
            asm volatile("s_waitcnt vmcnt(0)" ::: "memory");
        }
        __builtin_amdgcn_s_barrier();
        asm volatile("" ::: "memory");
        // C-init: s^T[k][q] starts at log2e*bias + mask (lane: q=w*16+col, k=t*16+q4*4+r)
        f32x4 s[4];
#pragma unroll
        for (int t = 0; t < 4; ++t) {
            const f32x4 ma = *(const f32x4*)&maskb[kt * 64 + t * 16 + q4 * 4];
            ushort4 ebv = *(const ushort4*)&EBsh[(w * 16 + col) * 64 +
                                                (((t * 16 + q4 * 4)) ^ ((col & 7) << 3))];
            s[t][0] = bf2f(ebv.x) + ma[0];
            s[t][1] = bf2f(ebv.y) + ma[1];
            s[t][2] = bf2f(ebv.z) + ma[2];
            s[t][3] = bf2f(ebv.w) + ma[3];
        }
        // S^T = K Q^T (+C): A = K-frag, B = Q-frag
        __builtin_amdgcn_s_setprio(1);
#pragma unroll
        for (int t = 0; t < 4; ++t) {
            int krow = t * 16 + col;
#pragma unroll
            for (int j = 0; j < 2; ++j) {
                bf16x8 kf = *(const bf16x8*)&Ksh[cur][(krow * 64 + q4 * 8 + j * 32) ^ ((krow & 7) << 3)];
                s[t] = __builtin_amdgcn_mfma_f32_16x16x32_bf16(kf, qf[j], s[t], 0, 0, 0);
            }
        }
        __builtin_amdgcn_s_setprio(0);
        // p = 2^s; per-lane scalar psum (single q-row per lane)
        float p[4][4];
#pragma unroll
        for (int t = 0; t < 4; ++t)
#pragma unroll
            for (int r = 0; r < 4; ++r) {
                float pv = exp2f(s[t][r]);
                p[t][r] = pv;
                psum += pv;
            }
        // EB consumed -> drain LDS queue, prefetch next EB tile
        asm volatile("s_waitcnt lgkmcnt(0)" ::: "memory");
        __builtin_amdgcn_sched_barrier(0);
        if (kt + 1 < NT) STAGE_EB(kt + 1);
        // P^T pack: 4 consecutive k per lane -> cvt_pk pairs, b64 writes into [16 q][64 k]
        unsigned short* pw = Psh[w];
#pragma unroll
        for (int t = 0; t < 4; ++t) {
            unsigned pk0, pk1;
            asm("v_cvt_pk_bf16_f32 %0, %1, %2" : "=v"(pk0) : "v"(p[t][0]), "v"(p[t][1]));
            asm("v_cvt_pk_bf16_f32 %0, %1, %2" : "=v"(pk1) : "v"(p[t][2]), "v"(p[t][3]));
            uint2 pk; pk.x = pk0; pk.y = pk1;
            *(uint2*)&pw[(col * 64) + (((t * 16 + q4 * 4)) ^ ((col & 7) << 3))] = pk;
        }
        // O += P V : A-frags (2, hoisted) from P rows q=col; B from V^T
        bf16x8 pa[2];
#pragma unroll
        for (int ksl = 0; ksl < 2; ++ksl)
            pa[ksl] = *(const bf16x8*)&pw[(col * 64) + ((ksl * 32 + q4 * 8) ^ ((col & 7) << 3))];
        __builtin_amdgcn_s_setprio(1);
#pragma unroll
        for (int ot = 0; ot < 4; ++ot) {
            int vrow = ot * 16 + col;
#pragma unroll
            for (int ksl = 0; ksl < 2; ++ksl) {
                bf16x8 vb = *(const bf16x8*)&Vsh[cur][(vrow * 64 + q4 * 8 + ksl * 32) ^ ((vrow & 7) << 3)];
                oacc[ot] = __builtin_amdgcn_mfma_f32_16x16x32_bf16(pa[ksl], vb, oacc[ot], 0, 0, 0);
            }
        }
        __builtin_amdgcn_s_setprio(0);
        __builtin_amdgcn_sched_barrier(0);   // pin cluster + its lgkm waits before the barrier
        asm volatile("" ::: "memory");
        __builtin_amdgcn_s_barrier();
    }
#undef STAGE_KV
#undef STAGE_EB
    // psum: reduce the 4 q4-copies of each q-col, then redistribute to C-layout rows
    psum += __shfl_xor(psum, 16);
    psum += __shfl_xor(psum, 32);
    float inv[4];
#pragma unroll
    for (int r = 0; r < 4; ++r)
        inv[r] = 1.0f / __shfl(psum, q4 * 4 + r);
    // epilogue: normalize and write o in (B, L, N*D) bf16
#pragma unroll
    for (int r = 0; r < 4; ++r) {
        int lg = qt * 64 + w * 16 + q4 * 4 + r;
#pragma unroll
        for (int ot = 0; ot < 4; ++ot)
            ob[(size_t)(b * Ls + lg) * DM + n * DH + ot * 16 + col] = f2bf(oacc[ot][r] * inv[r]);
    }
}

extern "C" void kernel_launch(void* const* d_in, const int* in_sizes, int n_in,
                              void* d_out, int out_size, void* d_ws, size_t ws_size,
                              hipStream_t stream) {
    const float* x     = (const float*)d_in[0];
    const float* posb  = (const float*)d_in[1];
    const float* qkv_w = (const float*)d_in[2];
    const float* qkv_b = (const float*)d_in[3];
    const float* out_w = (const float*)d_in[4];
    const float* out_b = (const float*)d_in[5];
    const int*   mask  = (const int*)d_in[6];
    float* out = (float*)d_out;

    char* wp = (char*)d_ws;
    auto alloc = [&](size_t bytes) {
        char* p = wp;
        wp += (bytes + 255) & ~(size_t)255;
        return p;
    };
    unsigned short* xb   = (unsigned short*)alloc((size_t)Bb * Ls * DM * 2);
    unsigned short* wqb  = (unsigned short*)alloc((size_t)QKV * DM * 2);
    unsigned short* wob  = (unsigned short*)alloc((size_t)DM * DM * 2);
    unsigned short* ebb  = (unsigned short*)alloc((size_t)NH * Ls * Ls * 2);
    float*          tab  = (float*)alloc((size_t)Ls * DH * 4);
    unsigned short* qsb  = (unsigned short*)alloc((size_t)Bb * NH * Ls * DH * 2);
    unsigned short* ksb  = (unsigned short*)alloc((size_t)Bb * NH * Ls * DH * 2);
    unsigned short* vtb  = (unsigned short*)alloc((size_t)Bb * NH * DH * Ls * 2);
    unsigned short* obb  = (unsigned short*)alloc((size_t)Bb * Ls * DM * 2);

    prep_kernel<<<dim3(2048), dim3(256), 0, stream>>>(x, qkv_w, out_w, posb, xb, wqb, wob, ebb, tab);
    gemm_qkv<<<dim3(1152), dim3(256), 0, stream>>>(wqb, xb, qkv_b, tab, qsb, ksb, vtb);
    attn_kernel<<<dim3(1536), dim3(256), 0, stream>>>(qsb, ksb, vtb, ebb, mask, obb);
    gemm_nt<0><<<dim3(384), dim3(256), 0, stream>>>(obb, wob, out_b, (void*)out, Bb * Ls, DM, DM);
}

// Round 7
// 264.005 us; speedup vs baseline: 1.1220x; 1.0177x over previous
//
#include <hip/hip_runtime.h>

#define DEVINL __device__ __forceinline__

using bf16x8 = __attribute__((ext_vector_type(8))) short;
using f32x4  = __attribute__((ext_vector_type(4))) float;

constexpr int Bb = 8, Ls = 1024, DM = 768, NH = 12, DH = 64;
constexpr int QKV = 3 * DM; // 2304

DEVINL unsigned short f2bf(float f) {
    union { float f; unsigned u; } v; v.f = f;
    unsigned r = v.u + 0x7FFFu + ((v.u >> 16) & 1u);
    return (unsigned short)(r >> 16);
}
DEVINL float bf2f(unsigned short h) {
    union { unsigned u; float f; } v; v.u = ((unsigned)h) << 16; return v.f;
}
DEVINL float asf(unsigned u) {
    union { unsigned u; float f; } v; v.u = u; return v.f;
}
DEVINL float fexp2(float x) {
#if __has_builtin(__builtin_amdgcn_exp2f)
    return __builtin_amdgcn_exp2f(x);
#else
    float r; asm("v_exp_f32 %0, %1\n\ts_nop 1" : "=v"(r) : "v"(x)); return r;
#endif
}

DEVINL void gload_lds16(const void* g, void* l) {
    __builtin_amdgcn_global_load_lds((const __attribute__((address_space(1))) void*)g,
                                     (__attribute__((address_space(3))) void*)l, 16, 0, 0);
}

// ---------------- prep: casts + log2e*pos_bias + interleaved (cos,sin) rope table ----------------
__global__ void prep_kernel(const float* __restrict__ x, const float* __restrict__ wq,
                            const float* __restrict__ wo, const float* __restrict__ pbias,
                            unsigned short* __restrict__ xb, unsigned short* __restrict__ wqb,
                            unsigned short* __restrict__ wob, unsigned short* __restrict__ ebb,
                            float* __restrict__ tab) {
    const int X4 = Bb * Ls * DM / 4, W4 = QKV * DM / 4, O4 = DM * DM / 4;
    const int E4 = NH * Ls * Ls / 4, TB = Ls * DH;
    const int total = X4 + W4 + O4 + E4 + TB;
    const float L2E = 1.44269504089f;
    for (int idx = blockIdx.x * blockDim.x + threadIdx.x; idx < total;
         idx += gridDim.x * blockDim.x) {
        if (idx < X4 + W4 + O4) {
            const float4* s; unsigned short* d; int i;
            if (idx < X4)            { s = (const float4*)x;  d = xb;  i = idx; }
            else if (idx < X4 + W4)  { s = (const float4*)wq; d = wqb; i = idx - X4; }
            else                     { s = (const float4*)wo; d = wob; i = idx - X4 - W4; }
            float4 v = s[i];
            ushort4 o;
            o.x = f2bf(v.x); o.y = f2bf(v.y); o.z = f2bf(v.z); o.w = f2bf(v.w);
            ((ushort4*)d)[i] = o;
        } else if (idx < X4 + W4 + O4 + E4) {
            int i = idx - (X4 + W4 + O4);
            float4 v = ((const float4*)pbias)[i];
            ushort4 o;
            o.x = f2bf(v.x * L2E); o.y = f2bf(v.y * L2E);
            o.z = f2bf(v.z * L2E); o.w = f2bf(v.w * L2E);
            ((ushort4*)ebb)[i] = o;
        } else {
            int r = idx - (X4 + W4 + O4 + E4);
            int l = r >> 6, c = r & 63, i = c >> 1;     // pair index; interleaved cos/sin
            float freq = powf(10000.0f, -(float)i / 32.0f);
            float ang = (float)l * freq;
            tab[l * 64 + c] = (c & 1) ? sinf(ang) : cosf(ang);
        }
    }
}

// ---------------- fused QKV GEMM^T + RoPE + V-transpose ----------------
__global__ __launch_bounds__(256) void gemm_qkv(const unsigned short* __restrict__ A,
                                                const unsigned short* __restrict__ Bw,
                                                const float* __restrict__ bias,
                                                const float* __restrict__ tab,
                                                unsigned short* __restrict__ qs,
                                                unsigned short* __restrict__ ks,
                                                unsigned short* __restrict__ vt) {
    constexpr int K = 768;
    __shared__ unsigned short Sh[16384];              // [As dbuf | Bs dbuf], 32KB
#define ASP(bi) (Sh + (bi)*4096)
#define BSP(bi) (Sh + 8192 + (bi)*4096)
    const int tid = threadIdx.x, lane = tid & 63, w = tid >> 6;
    const int f = blockIdx.x;
    const int bm = (f % 18) * 128, bn = (f / 18) * 128;
    const int wm = w >> 1, wn = w & 1;
    const int col = lane & 15, q4 = lane >> 4;
    f32x4 acc[4][4] = {};

#define GSTAGE(bi, kt_)                                                                   \
    {                                                                                     \
        _Pragma("unroll") for (int i = 0; i < 2; ++i) {                                   \
            int c0 = w * 128 + i * 64;                                                    \
            int p = c0 + lane;                                                            \
            int row = p >> 2;                                                             \
            int kc = (p & 3) ^ (row & 3);                                                 \
            gload_lds16(A + (size_t)(bm + row) * K + (kt_)*32 + kc * 8, ASP(bi) + c0 * 8);  \
            gload_lds16(Bw + (size_t)(bn + row) * K + (kt_)*32 + kc * 8, BSP(bi) + c0 * 8); \
        }                                                                                 \
    }

    const int NT = K / 32;
    GSTAGE(0, 0);
    for (int t = 0; t < NT; ++t) {
        const int cur = t & 1;
        if (t + 1 < NT) {
            GSTAGE(cur ^ 1, t + 1);
            asm volatile("s_waitcnt vmcnt(4)" ::: "memory");
        } else {
            asm volatile("s_waitcnt vmcnt(0)" ::: "memory");
        }
        __builtin_amdgcn_s_barrier();
        asm volatile("" ::: "memory");
        bf16x8 af[4], bfr[4];
#pragma unroll
        for (int tt = 0; tt < 4; ++tt) {
            int ra = wm * 64 + tt * 16 + col;
            int rb = wn * 64 + tt * 16 + col;
            af[tt]  = *(const bf16x8*)&ASP(cur)[(ra * 32 + q4 * 8) ^ ((ra & 3) << 3)];
            bfr[tt] = *(const bf16x8*)&BSP(cur)[(rb * 32 + q4 * 8) ^ ((rb & 3) << 3)];
        }
#pragma unroll
        for (int tt = 0; tt < 4; ++tt)
#pragma unroll
            for (int u = 0; u < 4; ++u)
                acc[tt][u] = __builtin_amdgcn_mfma_f32_16x16x32_bf16(af[tt], bfr[u], acc[tt][u], 0, 0, 0);
        __builtin_amdgcn_sched_barrier(0);
        asm volatile("" ::: "memory");
        __builtin_amdgcn_s_barrier();
    }
#undef GSTAGE
    // ---- epilogue: bias + rope (f32, lane-local pairs) -> LDS transpose -> stores ----
    __syncthreads();                                   // all waves done reading Sh
    unsigned short* tr = Sh + w * 4096;                // wave-private 64x64 bf16
    const int btype = bm / 768;                        // 0=q 1=k 2=v (tiles align)
    const int n = ((bm % 768) + wm * 64) >> 6;
    const float QS = (btype == 0) ? 0.125f * 1.44269504089f : 1.0f;
#pragma unroll
    for (int t = 0; t < 4; ++t) {
        const int dloc = t * 16 + q4 * 4;
        const int grow = bm + wm * 64 + dloc;
        float bv[4];
#pragma unroll
        for (int r = 0; r < 4; ++r) bv[r] = bias[grow + r];
#pragma unroll
        for (int u = 0; u < 4; ++u) {
            const int lt_ = u * 16 + col;
            if (btype < 2) {
                const int l = (bn + wn * 64 + lt_) & 1023;
                float4 cs = *(const float4*)&tab[l * 64 + dloc]; // c_i,s_i,c_{i+1},s_{i+1}
                float x0 = acc[t][u][0] + bv[0], x1 = acc[t][u][1] + bv[1];
                float x2 = acc[t][u][2] + bv[2], x3 = acc[t][u][3] + bv[3];
                ushort4 pk;
                pk.x = f2bf((x0 * cs.x - x1 * cs.y) * QS);
                pk.y = f2bf((x1 * cs.x + x0 * cs.y) * QS);
                pk.z = f2bf((x2 * cs.z - x3 * cs.w) * QS);
                pk.w = f2bf((x3 * cs.z + x2 * cs.w) * QS);
                *(ushort4*)&tr[lt_ * 64 + (dloc ^ ((lt_ & 7) << 3))] = pk;   // [tok][d]
            } else {
#pragma unroll
                for (int r = 0; r < 4; ++r) {
                    int dr = dloc + r;
                    tr[dr * 64 + (lt_ ^ ((dr & 7) << 3))] = f2bf(acc[t][u][r] + bv[r]); // [d][tok]
                }
            }
        }
    }
    asm volatile("s_waitcnt lgkmcnt(0)" ::: "memory");
    __builtin_amdgcn_sched_barrier(0);
    const int gt0 = bn + wn * 64;                      // 64 tokens, same batch
    const int b2 = gt0 >> 10;
    if (btype < 2) {
        const int l2 = (gt0 + lane) & 1023;
        unsigned short* dstp = (btype ? ks : qs) + ((size_t)(b2 * NH + n) * Ls + l2) * DH;
#pragma unroll
        for (int c8 = 0; c8 < 8; ++c8)
            *(bf16x8*)&dstp[c8 * 8] =
                *(const bf16x8*)&tr[lane * 64 + ((c8 * 8) ^ ((lane & 7) << 3))];
    } else {
        unsigned short* dstp = vt + ((size_t)(b2 * NH + n) * DH + lane) * Ls + (gt0 & 1023);
#pragma unroll
        for (int c8 = 0; c8 < 8; ++c8)
            *(bf16x8*)&dstp[c8 * 8] =
                *(const bf16x8*)&tr[lane * 64 + ((c8 * 8) ^ ((lane & 7) << 3))];
    }
#undef ASP
#undef BSP
}

// ---------------- bf16 NT GEMM (out-proj): C = A(MxK) * B(NxK)^T + bias, f32 out ----------------
template <int OUT_BF16>
__global__ __launch_bounds__(256) void gemm_nt(const unsigned short* __restrict__ A,
                                               const unsigned short* __restrict__ Bw,
                                               const float* __restrict__ bias,
                                               void* __restrict__ Cout,
                                               int M, int Nn, int K) {
    __shared__ unsigned short As[2][128 * 32];
    __shared__ unsigned short Bs[2][128 * 32];
    const int tid = threadIdx.x, lane = tid & 63, w = tid >> 6;
    const int f = blockIdx.x;
    const int bm = (8 * (f & 7) + ((f >> 3) & 7)) * 128;  // M/128 == 64 here
    const int bn = (f >> 6) * 128;
    const int wm = w >> 1, wn = w & 1;
    const int col = lane & 15, q4 = lane >> 4;
    f32x4 acc[4][4] = {};

#define GSTAGE(bi, kt_)                                                              \
    {                                                                                \
        _Pragma("unroll") for (int i = 0; i < 2; ++i) {                              \
            int c0 = w * 128 + i * 64;                                               \
            int p = c0 + lane;                                                       \
            int row = p >> 2;                                                        \
            int kc = (p & 3) ^ (row & 3);                                            \
            gload_lds16(A + (size_t)(bm + row) * K + (kt_)*32 + kc * 8, &As[bi][c0 * 8]); \
            gload_lds16(Bw + (size_t)(bn + row) * K + (kt_)*32 + kc * 8, &Bs[bi][c0 * 8]); \
        }                                                                            \
    }

    const int NT = K / 32;
    GSTAGE(0, 0);
    for (int t = 0; t < NT; ++t) {
        const int cur = t & 1;
        if (t + 1 < NT) {
            GSTAGE(cur ^ 1, t + 1);
            asm volatile("s_waitcnt vmcnt(4)" ::: "memory");
        } else {
            asm volatile("s_waitcnt vmcnt(0)" ::: "memory");
        }
        __builtin_amdgcn_s_barrier();
        asm volatile("" ::: "memory");
        bf16x8 af[4], bfr[4];
#pragma unroll
        for (int tt = 0; tt < 4; ++tt) {
            int ra = wm * 64 + tt * 16 + col;
            int rb = wn * 64 + tt * 16 + col;
            af[tt]  = *(const bf16x8*)&As[cur][(ra * 32 + q4 * 8) ^ ((ra & 3) << 3)];
            bfr[tt] = *(const bf16x8*)&Bs[cur][(rb * 32 + q4 * 8) ^ ((rb & 3) << 3)];
        }
#pragma unroll
        for (int tt = 0; tt < 4; ++tt)
#pragma unroll
            for (int u = 0; u < 4; ++u)
                acc[tt][u] = __builtin_amdgcn_mfma_f32_16x16x32_bf16(af[tt], bfr[u], acc[tt][u], 0, 0, 0);
        __builtin_amdgcn_sched_barrier(0);
        asm volatile("" ::: "memory");
        __builtin_amdgcn_s_barrier();
    }
#undef GSTAGE
#pragma unroll
    for (int t = 0; t < 4; ++t) {
        int grow_base = bm + wm * 64 + t * 16 + q4 * 4;
#pragma unroll
        for (int u = 0; u < 4; ++u) {
            int gcol = bn + wn * 64 + u * 16 + col;
            float bv = bias[gcol];
#pragma unroll
            for (int r = 0; r < 4; ++r) {
                float vv = acc[t][u][r] + bv;
                if (OUT_BF16)
                    ((unsigned short*)Cout)[(size_t)(grow_base + r) * Nn + gcol] = f2bf(vv);
                else
                    ((float*)Cout)[(size_t)(grow_base + r) * Nn + gcol] = vv;
            }
        }
    }
}

// ---------------- flash attention, swapped-operand S^T, EB+mask as MFMA C ----------------
// 1-D grid 1536, decode f = b*192 + t (t = n + 12*qt): same-EB blocks share an XCD.
__global__ __launch_bounds__(256) void attn_kernel(const unsigned short* __restrict__ qs,
                                                   const unsigned short* __restrict__ ks,
                                                   const unsigned short* __restrict__ vt,
                                                   const unsigned short* __restrict__ ebb,
                                                   const int* __restrict__ mask,
                                                   unsigned short* __restrict__ ob) {
    __shared__ unsigned short Ksh[2][64 * 64];
    __shared__ unsigned short Vsh[2][64 * 64];
    __shared__ unsigned short EBsh[64 * 64];
    __shared__ unsigned short Psh[4][16 * 64];
    __shared__ float maskb[Ls];
    const int f = blockIdx.x;
    const int b = f / 192, t192 = f % 192;
    const int n = t192 % 12, qt = t192 / 12;
    const int tid = threadIdx.x, lane = tid & 63, w = tid >> 6;
    const int col = lane & 15, q4 = lane >> 4;
    for (int i = tid; i < Ls; i += 256)
        maskb[i] = (mask[b * Ls + i] > 0) ? 0.0f : -1e30f;
    const unsigned short* qbn = qs + (size_t)(b * NH + n) * Ls * DH;
    const unsigned short* kbn = ks + (size_t)(b * NH + n) * Ls * DH;
    const unsigned short* vbn = vt + (size_t)(b * NH + n) * DH * Ls;
    const unsigned short* ebn = ebb + (size_t)n * Ls * Ls;
    bf16x8 qf[2];
#pragma unroll
    for (int j = 0; j < 2; ++j)
        qf[j] = *(const bf16x8*)(qbn + (size_t)(qt * 64 + w * 16 + col) * DH + q4 * 8 + j * 32);
    float psum = 0.f;            // lane owns q = w*16+col
    f32x4 oacc[4];
#pragma unroll
    for (int t = 0; t < 4; ++t) oacc[t] = f32x4{0.f, 0.f, 0.f, 0.f};
    __syncthreads(); // maskb visible to all waves

#define STAGE_KV(bi, kt_)                                                                  \
    {                                                                                      \
        _Pragma("unroll") for (int i = 0; i < 2; ++i) {                                    \
            int c0 = w * 128 + i * 64;                                                     \
            int p = c0 + lane;                                                             \
            int row = p >> 3, cin = (p & 7) ^ (row & 7);                                   \
            gload_lds16(kbn + (size_t)((kt_)*64 + row) * DH + cin * 8, &Ksh[bi][c0 * 8]);  \
            gload_lds16(vbn + (size_t)row * Ls + (kt_)*64 + cin * 8, &Vsh[bi][c0 * 8]);    \
        }                                                                                  \
    }
#define STAGE_EB(kt_)                                                                      \
    {                                                                                      \
        _Pragma("unroll") for (int i = 0; i < 2; ++i) {                                    \
            int c0 = w * 128 + i * 64;                                                     \
            int p = c0 + lane;                                                             \
            int row = p >> 3, cin = (p & 7) ^ (row & 7);                                   \
            gload_lds16(ebn + (size_t)(qt * 64 + row) * Ls + (kt_)*64 + cin * 8, &EBsh[c0 * 8]); \
        }                                                                                  \
    }

    const int NT = Ls / 64;
    STAGE_KV(0, 0);
    STAGE_EB(0);
#pragma unroll 2
    for (int kt = 0; kt < NT; ++kt) {
        const int cur = kt & 1;
        if (kt + 1 < NT) {
            STAGE_KV(cur ^ 1, kt + 1);
            asm volatile("s_waitcnt vmcnt(4)" ::: "memory"); // K/V/EB of tile kt landed
        } else {
            asm volatile("s_waitcnt vmcnt(0)" ::: "memory");
        }
        __builtin_amdgcn_s_barrier();
        asm volatile("" ::: "memory");
        // C-init: s^T[k][q] starts at log2e*bias + mask (lane: q=w*16+col, k=t*16+q4*4+r)
        f32x4 s[4];
#pragma unroll
        for (int t = 0; t < 4; ++t) {
            const f32x4 ma = *(const f32x4*)&maskb[kt * 64 + t * 16 + q4 * 4];
            uint2 ebv = *(const uint2*)&EBsh[(w * 16 + col) * 64 +
                                            (((t * 16 + q4 * 4)) ^ ((col & 7) << 3))];
            s[t][0] = asf(ebv.x << 16)          + ma[0];
            s[t][1] = asf(ebv.x & 0xffff0000u)  + ma[1];
            s[t][2] = asf(ebv.y << 16)          + ma[2];
            s[t][3] = asf(ebv.y & 0xffff0000u)  + ma[3];
        }
        // S^T = K Q^T (+C): A = K-frag, B = Q-frag
        __builtin_amdgcn_s_setprio(1);
#pragma unroll
        for (int t = 0; t < 4; ++t) {
            int krow = t * 16 + col;
#pragma unroll
            for (int j = 0; j < 2; ++j) {
                bf16x8 kf = *(const bf16x8*)&Ksh[cur][(krow * 64 + q4 * 8 + j * 32) ^ ((krow & 7) << 3)];
                s[t] = __builtin_amdgcn_mfma_f32_16x16x32_bf16(kf, qf[j], s[t], 0, 0, 0);
            }
        }
        __builtin_amdgcn_s_setprio(0);
        // p = 2^s via raw v_exp_f32; per-lane scalar psum (single q-row per lane)
        float p[4][4];
#pragma unroll
        for (int t = 0; t < 4; ++t)
#pragma unroll
            for (int r = 0; r < 4; ++r) {
                float pv = fexp2(s[t][r]);
                p[t][r] = pv;
                psum += pv;
            }
        // EB consumed -> drain LDS queue, prefetch next EB tile
        asm volatile("s_waitcnt lgkmcnt(0)" ::: "memory");
        __builtin_amdgcn_sched_barrier(0);
        if (kt + 1 < NT) STAGE_EB(kt + 1);
        // P^T pack: 4 consecutive k per lane -> cvt_pk pairs, b64 writes into [16 q][64 k]
        unsigned short* pw = Psh[w];
#pragma unroll
        for (int t = 0; t < 4; ++t) {
            unsigned pk0, pk1;
            asm("v_cvt_pk_bf16_f32 %0, %1, %2" : "=v"(pk0) : "v"(p[t][0]), "v"(p[t][1]));
            asm("v_cvt_pk_bf16_f32 %0, %1, %2" : "=v"(pk1) : "v"(p[t][2]), "v"(p[t][3]));
            uint2 pk; pk.x = pk0; pk.y = pk1;
            *(uint2*)&pw[(col * 64) + (((t * 16 + q4 * 4)) ^ ((col & 7) << 3))] = pk;
        }
        // O += P V : A-frags (2, hoisted) from P rows q=col; B from V^T
        bf16x8 pa[2];
#pragma unroll
        for (int ksl = 0; ksl < 2; ++ksl)
            pa[ksl] = *(const bf16x8*)&pw[(col * 64) + ((ksl * 32 + q4 * 8) ^ ((col & 7) << 3))];
        __builtin_amdgcn_s_setprio(1);
#pragma unroll
        for (int ot = 0; ot < 4; ++ot) {
            int vrow = ot * 16 + col;
#pragma unroll
            for (int ksl = 0; ksl < 2; ++ksl) {
                bf16x8 vb = *(const bf16x8*)&Vsh[cur][(vrow * 64 + q4 * 8 + ksl * 32) ^ ((vrow & 7) << 3)];
                oacc[ot] = __builtin_amdgcn_mfma_f32_16x16x32_bf16(pa[ksl], vb, oacc[ot], 0, 0, 0);
            }
        }
        __builtin_amdgcn_s_setprio(0);
        __builtin_amdgcn_sched_barrier(0);   // pin cluster + its lgkm waits before the barrier
        asm volatile("" ::: "memory");
        __builtin_amdgcn_s_barrier();
    }
#undef STAGE_KV
#undef STAGE_EB
    // psum: reduce the 4 q4-copies of each q-col, then redistribute to C-layout rows
    psum += __shfl_xor(psum, 16);
    psum += __shfl_xor(psum, 32);
    float inv[4];
#pragma unroll
    for (int r = 0; r < 4; ++r)
        inv[r] = 1.0f / __shfl(psum, q4 * 4 + r);
    // epilogue: normalize and write o in (B, L, N*D) bf16
#pragma unroll
    for (int r = 0; r < 4; ++r) {
        int lg = qt * 64 + w * 16 + q4 * 4 + r;
#pragma unroll
        for (int ot = 0; ot < 4; ++ot)
            ob[(size_t)(b * Ls + lg) * DM + n * DH + ot * 16 + col] = f2bf(oacc[ot][r] * inv[r]);
    }
}

extern "C" void kernel_launch(void* const* d_in, const int* in_sizes, int n_in,
                              void* d_out, int out_size, void* d_ws, size_t ws_size,
                              hipStream_t stream) {
    const float* x     = (const float*)d_in[0];
    const float* posb  = (const float*)d_in[1];
    const float* qkv_w = (const float*)d_in[2];
    const float* qkv_b = (const float*)d_in[3];
    const float* out_w = (const float*)d_in[4];
    const float* out_b = (const float*)d_in[5];
    const int*   mask  = (const int*)d_in[6];
    float* out = (float*)d_out;

    char* wp = (char*)d_ws;
    auto alloc = [&](size_t bytes) {
        char* p = wp;
        wp += (bytes + 255) & ~(size_t)255;
        return p;
    };
    unsigned short* xb   = (unsigned short*)alloc((size_t)Bb * Ls * DM * 2);
    unsigned short* wqb  = (unsigned short*)alloc((size_t)QKV * DM * 2);
    unsigned short* wob  = (unsigned short*)alloc((size_t)DM * DM * 2);
    unsigned short* ebb  = (unsigned short*)alloc((size_t)NH * Ls * Ls * 2);
    float*          tab  = (float*)alloc((size_t)Ls * DH * 4);
    unsigned short* qsb  = (unsigned short*)alloc((size_t)Bb * NH * Ls * DH * 2);
    unsigned short* ksb  = (unsigned short*)alloc((size_t)Bb * NH * Ls * DH * 2);
    unsigned short* vtb  = (unsigned short*)alloc((size_t)Bb * NH * DH * Ls * 2);
    unsigned short* obb  = (unsigned short*)alloc((size_t)Bb * Ls * DM * 2);

    prep_kernel<<<dim3(2048), dim3(256), 0, stream>>>(x, qkv_w, out_w, posb, xb, wqb, wob, ebb, tab);
    gemm_qkv<<<dim3(1152), dim3(256), 0, stream>>>(wqb, xb, qkv_b, tab, qsb, ksb, vtb);
    attn_kernel<<<dim3(1536), dim3(256), 0, stream>>>(qsb, ksb, vtb, ebb, mask, obb);
    gemm_nt<0><<<dim3(384), dim3(256), 0, stream>>>(obb, wob, out_b, (void*)out, Bb * Ls, DM, DM);
}

// Round 8
// 261.778 us; speedup vs baseline: 1.1316x; 1.0085x over previous
//
#include <hip/hip_runtime.h>

#define DEVINL __device__ __forceinline__

using bf16x8 = __attribute__((ext_vector_type(8))) short;
using f32x4  = __attribute__((ext_vector_type(4))) float;

constexpr int Bb = 8, Ls = 1024, DM = 768, NH = 12, DH = 64;
constexpr int QKV = 3 * DM; // 2304

DEVINL unsigned short f2bf(float f) {
    union { float f; unsigned u; } v; v.f = f;
    unsigned r = v.u + 0x7FFFu + ((v.u >> 16) & 1u);
    return (unsigned short)(r >> 16);
}
DEVINL float bf2f(unsigned short h) {
    union { unsigned u; float f; } v; v.u = ((unsigned)h) << 16; return v.f;
}
DEVINL float asf(unsigned u) {
    union { unsigned u; float f; } v; v.u = u; return v.f;
}
DEVINL float fexp2(float x) {
#if __has_builtin(__builtin_amdgcn_exp2f)
    return __builtin_amdgcn_exp2f(x);
#else
    float r; asm("v_exp_f32 %0, %1\n\ts_nop 1" : "=v"(r) : "v"(x)); return r;
#endif
}

DEVINL void gload_lds16(const void* g, void* l) {
    __builtin_amdgcn_global_load_lds((const __attribute__((address_space(1))) void*)g,
                                     (__attribute__((address_space(3))) void*)l, 16, 0, 0);
}

// ---------------- prep: casts + log2e*pos_bias + interleaved (cos,sin) rope table ----------------
__global__ void prep_kernel(const float* __restrict__ x, const float* __restrict__ wq,
                            const float* __restrict__ wo, const float* __restrict__ pbias,
                            unsigned short* __restrict__ xb, unsigned short* __restrict__ wqb,
                            unsigned short* __restrict__ wob, unsigned short* __restrict__ ebb,
                            float* __restrict__ tab) {
    const int X4 = Bb * Ls * DM / 4, W4 = QKV * DM / 4, O4 = DM * DM / 4;
    const int E4 = NH * Ls * Ls / 4, TB = Ls * DH;
    const int total = X4 + W4 + O4 + E4 + TB;
    const float L2E = 1.44269504089f;
    for (int idx = blockIdx.x * blockDim.x + threadIdx.x; idx < total;
         idx += gridDim.x * blockDim.x) {
        if (idx < X4 + W4 + O4) {
            const float4* s; unsigned short* d; int i;
            if (idx < X4)            { s = (const float4*)x;  d = xb;  i = idx; }
            else if (idx < X4 + W4)  { s = (const float4*)wq; d = wqb; i = idx - X4; }
            else                     { s = (const float4*)wo; d = wob; i = idx - X4 - W4; }
            float4 v = s[i];
            ushort4 o;
            o.x = f2bf(v.x); o.y = f2bf(v.y); o.z = f2bf(v.z); o.w = f2bf(v.w);
            ((ushort4*)d)[i] = o;
        } else if (idx < X4 + W4 + O4 + E4) {
            int i = idx - (X4 + W4 + O4);
            float4 v = ((const float4*)pbias)[i];
            ushort4 o;
            o.x = f2bf(v.x * L2E); o.y = f2bf(v.y * L2E);
            o.z = f2bf(v.z * L2E); o.w = f2bf(v.w * L2E);
            ((ushort4*)ebb)[i] = o;
        } else {
            int r = idx - (X4 + W4 + O4 + E4);
            int l = r >> 6, c = r & 63, i = c >> 1;     // pair index; interleaved cos/sin
            float freq = powf(10000.0f, -(float)i / 32.0f);
            float ang = (float)l * freq;
            tab[l * 64 + c] = (c & 1) ? sinf(ang) : cosf(ang);
        }
    }
}

// ---------------- fused QKV GEMM^T + RoPE + V-transpose ----------------
// Epilogue transpose LDS: stride-72 rows (144B, 16B-aligned) + chunk-XOR
// (c8 ^ (row&7)) so row contributes 4*(row%8) to the bank index -> ~2-way.
__global__ __launch_bounds__(256) void gemm_qkv(const unsigned short* __restrict__ A,
                                                const unsigned short* __restrict__ Bw,
                                                const float* __restrict__ bias,
                                                const float* __restrict__ tab,
                                                unsigned short* __restrict__ qs,
                                                unsigned short* __restrict__ ks,
                                                unsigned short* __restrict__ vt) {
    constexpr int K = 768;
    __shared__ unsigned short Sh[18432];   // GEMM: first 16384; epilogue: 4 x (64x72)
#define ASP(bi) (Sh + (bi)*4096)
#define BSP(bi) (Sh + 8192 + (bi)*4096)
    const int tid = threadIdx.x, lane = tid & 63, w = tid >> 6;
    const int f = blockIdx.x;
    const int bm = (f % 18) * 128, bn = (f / 18) * 128;
    const int wm = w >> 1, wn = w & 1;
    const int col = lane & 15, q4 = lane >> 4;
    f32x4 acc[4][4] = {};

#define GSTAGE(bi, kt_)                                                                   \
    {                                                                                     \
        _Pragma("unroll") for (int i = 0; i < 2; ++i) {                                   \
            int c0 = w * 128 + i * 64;                                                    \
            int p = c0 + lane;                                                            \
            int row = p >> 2;                                                             \
            int kc = (p & 3) ^ (row & 3);                                                 \
            gload_lds16(A + (size_t)(bm + row) * K + (kt_)*32 + kc * 8, ASP(bi) + c0 * 8);  \
            gload_lds16(Bw + (size_t)(bn + row) * K + (kt_)*32 + kc * 8, BSP(bi) + c0 * 8); \
        }                                                                                 \
    }

    const int NT = K / 32;
    GSTAGE(0, 0);
#pragma unroll 2
    for (int t = 0; t < NT; ++t) {
        const int cur = t & 1;
        if (t + 1 < NT) {
            GSTAGE(cur ^ 1, t + 1);
            asm volatile("s_waitcnt vmcnt(4)" ::: "memory");
        } else {
            asm volatile("s_waitcnt vmcnt(0)" ::: "memory");
        }
        __builtin_amdgcn_s_barrier();
        asm volatile("" ::: "memory");
        bf16x8 af[4], bfr[4];
#pragma unroll
        for (int tt = 0; tt < 4; ++tt) {
            int ra = wm * 64 + tt * 16 + col;
            int rb = wn * 64 + tt * 16 + col;
            af[tt]  = *(const bf16x8*)&ASP(cur)[(ra * 32 + q4 * 8) ^ ((ra & 3) << 3)];
            bfr[tt] = *(const bf16x8*)&BSP(cur)[(rb * 32 + q4 * 8) ^ ((rb & 3) << 3)];
        }
#pragma unroll
        for (int tt = 0; tt < 4; ++tt)
#pragma unroll
            for (int u = 0; u < 4; ++u)
                acc[tt][u] = __builtin_amdgcn_mfma_f32_16x16x32_bf16(af[tt], bfr[u], acc[tt][u], 0, 0, 0);
        __builtin_amdgcn_sched_barrier(0);
        asm volatile("" ::: "memory");
        __builtin_amdgcn_s_barrier();
    }
#undef GSTAGE
    // ---- epilogue: bias + rope (f32, lane-local pairs) -> LDS transpose -> stores ----
    __syncthreads();                                   // all waves done reading Sh
    unsigned short* tr = Sh + w * 4608;                // wave-private 64 x stride-72
    const int btype = bm / 768;                        // 0=q 1=k 2=v (tiles align)
    const int n = ((bm % 768) + wm * 64) >> 6;
    const float QS = (btype == 0) ? 0.125f * 1.44269504089f : 1.0f;
#pragma unroll
    for (int t = 0; t < 4; ++t) {
        const int dloc = t * 16 + q4 * 4;
        const int grow = bm + wm * 64 + dloc;
        float bv[4];
#pragma unroll
        for (int r = 0; r < 4; ++r) bv[r] = bias[grow + r];
#pragma unroll
        for (int u = 0; u < 4; ++u) {
            const int lt_ = u * 16 + col;
            if (btype < 2) {
                const int l = (bn + wn * 64 + lt_) & 1023;
                float4 cs = *(const float4*)&tab[l * 64 + dloc]; // c_i,s_i,c_{i+1},s_{i+1}
                float x0 = acc[t][u][0] + bv[0], x1 = acc[t][u][1] + bv[1];
                float x2 = acc[t][u][2] + bv[2], x3 = acc[t][u][3] + bv[3];
                ushort4 pk;
                pk.x = f2bf((x0 * cs.x - x1 * cs.y) * QS);
                pk.y = f2bf((x1 * cs.x + x0 * cs.y) * QS);
                pk.z = f2bf((x2 * cs.z - x3 * cs.w) * QS);
                pk.w = f2bf((x3 * cs.z + x2 * cs.w) * QS);
                // row = tok (lt_), chunk = dloc>>3, within = (q4&1)*4
                *(ushort4*)&tr[lt_ * 72 + (((2 * t + (q4 >> 1)) ^ (lt_ & 7)) << 3) + (q4 & 1) * 4] = pk;
            } else {
#pragma unroll
                for (int r = 0; r < 4; ++r) {
                    int dr = dloc + r;   // row = d, chunk = lt_>>3, within = lt_&7
                    tr[dr * 72 + ((((lt_ >> 3)) ^ (dr & 7)) << 3) + (lt_ & 7)] =
                        f2bf(acc[t][u][r] + bv[r]);
                }
            }
        }
    }
    asm volatile("s_waitcnt lgkmcnt(0)" ::: "memory");
    __builtin_amdgcn_sched_barrier(0);
    const int gt0 = bn + wn * 64;                      // 64 tokens, same batch
    const int b2 = gt0 >> 10;
    if (btype < 2) {
        const int l2 = (gt0 + lane) & 1023;
        unsigned short* dstp = (btype ? ks : qs) + ((size_t)(b2 * NH + n) * Ls + l2) * DH;
#pragma unroll
        for (int c8 = 0; c8 < 8; ++c8)
            *(bf16x8*)&dstp[c8 * 8] =
                *(const bf16x8*)&tr[lane * 72 + ((c8 ^ (lane & 7)) << 3)];
    } else {
        unsigned short* dstp = vt + ((size_t)(b2 * NH + n) * DH + lane) * Ls + (gt0 & 1023);
#pragma unroll
        for (int c8 = 0; c8 < 8; ++c8)
            *(bf16x8*)&dstp[c8 * 8] =
                *(const bf16x8*)&tr[lane * 72 + ((c8 ^ (lane & 7)) << 3)];
    }
#undef ASP
#undef BSP
}

// ---------------- bf16 NT GEMM (out-proj): C = A(MxK) * B(NxK)^T + bias, f32 out ----------------
template <int OUT_BF16>
__global__ __launch_bounds__(256) void gemm_nt(const unsigned short* __restrict__ A,
                                               const unsigned short* __restrict__ Bw,
                                               const float* __restrict__ bias,
                                               void* __restrict__ Cout,
                                               int M, int Nn, int K) {
    __shared__ unsigned short As[2][128 * 32];
    __shared__ unsigned short Bs[2][128 * 32];
    const int tid = threadIdx.x, lane = tid & 63, w = tid >> 6;
    const int f = blockIdx.x;
    const int bm = (8 * (f & 7) + ((f >> 3) & 7)) * 128;  // M/128 == 64 here
    const int bn = (f >> 6) * 128;
    const int wm = w >> 1, wn = w & 1;
    const int col = lane & 15, q4 = lane >> 4;
    f32x4 acc[4][4] = {};

#define GSTAGE(bi, kt_)                                                              \
    {                                                                                \
        _Pragma("unroll") for (int i = 0; i < 2; ++i) {                              \
            int c0 = w * 128 + i * 64;                                               \
            int p = c0 + lane;                                                       \
            int row = p >> 2;                                                        \
            int kc = (p & 3) ^ (row & 3);                                            \
            gload_lds16(A + (size_t)(bm + row) * K + (kt_)*32 + kc * 8, &As[bi][c0 * 8]); \
            gload_lds16(Bw + (size_t)(bn + row) * K + (kt_)*32 + kc * 8, &Bs[bi][c0 * 8]); \
        }                                                                            \
    }

    const int NT = K / 32;
    GSTAGE(0, 0);
#pragma unroll 2
    for (int t = 0; t < NT; ++t) {
        const int cur = t & 1;
        if (t + 1 < NT) {
            GSTAGE(cur ^ 1, t + 1);
            asm volatile("s_waitcnt vmcnt(4)" ::: "memory");
        } else {
            asm volatile("s_waitcnt vmcnt(0)" ::: "memory");
        }
        __builtin_amdgcn_s_barrier();
        asm volatile("" ::: "memory");
        bf16x8 af[4], bfr[4];
#pragma unroll
        for (int tt = 0; tt < 4; ++tt) {
            int ra = wm * 64 + tt * 16 + col;
            int rb = wn * 64 + tt * 16 + col;
            af[tt]  = *(const bf16x8*)&As[cur][(ra * 32 + q4 * 8) ^ ((ra & 3) << 3)];
            bfr[tt] = *(const bf16x8*)&Bs[cur][(rb * 32 + q4 * 8) ^ ((rb & 3) << 3)];
        }
#pragma unroll
        for (int tt = 0; tt < 4; ++tt)
#pragma unroll
            for (int u = 0; u < 4; ++u)
                acc[tt][u] = __builtin_amdgcn_mfma_f32_16x16x32_bf16(af[tt], bfr[u], acc[tt][u], 0, 0, 0);
        __builtin_amdgcn_sched_barrier(0);
        asm volatile("" ::: "memory");
        __builtin_amdgcn_s_barrier();
    }
#undef GSTAGE
#pragma unroll
    for (int t = 0; t < 4; ++t) {
        int grow_base = bm + wm * 64 + t * 16 + q4 * 4;
#pragma unroll
        for (int u = 0; u < 4; ++u) {
            int gcol = bn + wn * 64 + u * 16 + col;
            float bv = bias[gcol];
#pragma unroll
            for (int r = 0; r < 4; ++r) {
                float vv = acc[t][u][r] + bv;
                if (OUT_BF16)
                    ((unsigned short*)Cout)[(size_t)(grow_base + r) * Nn + gcol] = f2bf(vv);
                else
                    ((float*)Cout)[(size_t)(grow_base + r) * Nn + gcol] = vv;
            }
        }
    }
}

// ---------------- flash attention, swapped-operand S^T, EB+mask as MFMA C ----------------
// 1-D grid 1536, decode f = b*192 + t (t = n + 12*qt): same-EB blocks share an XCD.
// Row-sums via ones-column MFMA (sacc) -> no per-tile VALU adds, no final shuffles.
__global__ __launch_bounds__(256) void attn_kernel(const unsigned short* __restrict__ qs,
                                                   const unsigned short* __restrict__ ks,
                                                   const unsigned short* __restrict__ vt,
                                                   const unsigned short* __restrict__ ebb,
                                                   const int* __restrict__ mask,
                                                   unsigned short* __restrict__ ob) {
    __shared__ unsigned short Ksh[2][64 * 64];
    __shared__ unsigned short Vsh[2][64 * 64];
    __shared__ unsigned short EBsh[64 * 64];
    __shared__ unsigned short Psh[4][16 * 64];
    __shared__ float maskb[Ls];
    const int f = blockIdx.x;
    const int b = f / 192, t192 = f % 192;
    const int n = t192 % 12, qt = t192 / 12;
    const int tid = threadIdx.x, lane = tid & 63, w = tid >> 6;
    const int col = lane & 15, q4 = lane >> 4;
    for (int i = tid; i < Ls; i += 256)
        maskb[i] = (mask[b * Ls + i] > 0) ? 0.0f : -1e30f;
    const unsigned short* qbn = qs + (size_t)(b * NH + n) * Ls * DH;
    const unsigned short* kbn = ks + (size_t)(b * NH + n) * Ls * DH;
    const unsigned short* vbn = vt + (size_t)(b * NH + n) * DH * Ls;
    const unsigned short* ebn = ebb + (size_t)n * Ls * Ls;
    bf16x8 qf[2];
#pragma unroll
    for (int j = 0; j < 2; ++j)
        qf[j] = *(const bf16x8*)(qbn + (size_t)(qt * 64 + w * 16 + col) * DH + q4 * 8 + j * 32);
    bf16x8 vone;
#pragma unroll
    for (int j = 0; j < 8; ++j) vone[j] = (short)0x3F80;   // bf16 1.0
    f32x4 oacc[4];
#pragma unroll
    for (int t = 0; t < 4; ++t) oacc[t] = f32x4{0.f, 0.f, 0.f, 0.f};
    f32x4 sacc = f32x4{0.f, 0.f, 0.f, 0.f};               // row-sums, C-layout rows
    __syncthreads(); // maskb visible to all waves

#define STAGE_KV(bi, kt_)                                                                  \
    {                                                                                      \
        _Pragma("unroll") for (int i = 0; i < 2; ++i) {                                    \
            int c0 = w * 128 + i * 64;                                                     \
            int p = c0 + lane;                                                             \
            int row = p >> 3, cin = (p & 7) ^ (row & 7);                                   \
            gload_lds16(kbn + (size_t)((kt_)*64 + row) * DH + cin * 8, &Ksh[bi][c0 * 8]);  \
            gload_lds16(vbn + (size_t)row * Ls + (kt_)*64 + cin * 8, &Vsh[bi][c0 * 8]);    \
        }                                                                                  \
    }
#define STAGE_EB(kt_)                                                                      \
    {                                                                                      \
        _Pragma("unroll") for (int i = 0; i < 2; ++i) {                                    \
            int c0 = w * 128 + i * 64;                                                     \
            int p = c0 + lane;                                                             \
            int row = p >> 3, cin = (p & 7) ^ (row & 7);                                   \
            gload_lds16(ebn + (size_t)(qt * 64 + row) * Ls + (kt_)*64 + cin * 8, &EBsh[c0 * 8]); \
        }                                                                                  \
    }

    const int NT = Ls / 64;
    STAGE_KV(0, 0);
    STAGE_EB(0);
#pragma unroll 2
    for (int kt = 0; kt < NT; ++kt) {
        const int cur = kt & 1;
        if (kt + 1 < NT) {
            STAGE_KV(cur ^ 1, kt + 1);
            asm volatile("s_waitcnt vmcnt(4)" ::: "memory"); // K/V/EB of tile kt landed
        } else {
            asm volatile("s_waitcnt vmcnt(0)" ::: "memory");
        }
        __builtin_amdgcn_s_barrier();
        asm volatile("" ::: "memory");
        // C-init: s^T[k][q] starts at log2e*bias + mask (lane: q=w*16+col, k=t*16+q4*4+r)
        f32x4 s[4];
#pragma unroll
        for (int t = 0; t < 4; ++t) {
            const f32x4 ma = *(const f32x4*)&maskb[kt * 64 + t * 16 + q4 * 4];
            uint2 ebv = *(const uint2*)&EBsh[(w * 16 + col) * 64 +
                                            (((t * 16 + q4 * 4)) ^ ((col & 7) << 3))];
            s[t][0] = asf(ebv.x << 16)          + ma[0];
            s[t][1] = asf(ebv.x & 0xffff0000u)  + ma[1];
            s[t][2] = asf(ebv.y << 16)          + ma[2];
            s[t][3] = asf(ebv.y & 0xffff0000u)  + ma[3];
        }
        // S^T = K Q^T (+C): A = K-frag, B = Q-frag
        __builtin_amdgcn_s_setprio(1);
#pragma unroll
        for (int t = 0; t < 4; ++t) {
            int krow = t * 16 + col;
#pragma unroll
            for (int j = 0; j < 2; ++j) {
                bf16x8 kf = *(const bf16x8*)&Ksh[cur][(krow * 64 + q4 * 8 + j * 32) ^ ((krow & 7) << 3)];
                s[t] = __builtin_amdgcn_mfma_f32_16x16x32_bf16(kf, qf[j], s[t], 0, 0, 0);
            }
        }
        __builtin_amdgcn_s_setprio(0);
        // p = 2^s via raw v_exp_f32 (row-sum deferred to the ones-MFMA below)
        float p[4][4];
#pragma unroll
        for (int t = 0; t < 4; ++t)
#pragma unroll
            for (int r = 0; r < 4; ++r)
                p[t][r] = fexp2(s[t][r]);
        // EB consumed -> drain LDS queue, prefetch next EB tile
        asm volatile("s_waitcnt lgkmcnt(0)" ::: "memory");
        __builtin_amdgcn_sched_barrier(0);
        if (kt + 1 < NT) STAGE_EB(kt + 1);
        // P^T pack: 4 consecutive k per lane -> cvt_pk pairs, b64 writes into [16 q][64 k]
        unsigned short* pw = Psh[w];
#pragma unroll
        for (int t = 0; t < 4; ++t) {
            unsigned pk0, pk1;
            asm("v_cvt_pk_bf16_f32 %0, %1, %2" : "=v"(pk0) : "v"(p[t][0]), "v"(p[t][1]));
            asm("v_cvt_pk_bf16_f32 %0, %1, %2" : "=v"(pk1) : "v"(p[t][2]), "v"(p[t][3]));
            uint2 pk; pk.x = pk0; pk.y = pk1;
            *(uint2*)&pw[(col * 64) + (((t * 16 + q4 * 4)) ^ ((col & 7) << 3))] = pk;
        }
        // O += P V ; sacc += P * ones (row-sums in C-layout). A-frags hoisted.
        bf16x8 pa[2];
#pragma unroll
        for (int ksl = 0; ksl < 2; ++ksl)
            pa[ksl] = *(const bf16x8*)&pw[(col * 64) + ((ksl * 32 + q4 * 8) ^ ((col & 7) << 3))];
        __builtin_amdgcn_s_setprio(1);
#pragma unroll
        for (int ot = 0; ot < 4; ++ot) {
            int vrow = ot * 16 + col;
#pragma unroll
            for (int ksl = 0; ksl < 2; ++ksl) {
                bf16x8 vb = *(const bf16x8*)&Vsh[cur][(vrow * 64 + q4 * 8 + ksl * 32) ^ ((vrow & 7) << 3)];
                oacc[ot] = __builtin_amdgcn_mfma_f32_16x16x32_bf16(pa[ksl], vb, oacc[ot], 0, 0, 0);
            }
        }
        sacc = __builtin_amdgcn_mfma_f32_16x16x32_bf16(pa[0], vone, sacc, 0, 0, 0);
        sacc = __builtin_amdgcn_mfma_f32_16x16x32_bf16(pa[1], vone, sacc, 0, 0, 0);
        __builtin_amdgcn_s_setprio(0);
        __builtin_amdgcn_sched_barrier(0);   // pin cluster + its lgkm waits before the barrier
        asm volatile("" ::: "memory");
        __builtin_amdgcn_s_barrier();
    }
#undef STAGE_KV
#undef STAGE_EB
    // sacc[r] == psum[q4*4+r] already (same for all 16 cols)
    float inv[4];
#pragma unroll
    for (int r = 0; r < 4; ++r)
        inv[r] = 1.0f / sacc[r];
    // epilogue: normalize and write o in (B, L, N*D) bf16
#pragma unroll
    for (int r = 0; r < 4; ++r) {
        int lg = qt * 64 + w * 16 + q4 * 4 + r;
#pragma unroll
        for (int ot = 0; ot < 4; ++ot)
            ob[(size_t)(b * Ls + lg) * DM + n * DH + ot * 16 + col] = f2bf(oacc[ot][r] * inv[r]);
    }
}

extern "C" void kernel_launch(void* const* d_in, const int* in_sizes, int n_in,
                              void* d_out, int out_size, void* d_ws, size_t ws_size,
                              hipStream_t stream) {
    const float* x     = (const float*)d_in[0];
    const float* posb  = (const float*)d_in[1];
    const float* qkv_w = (const float*)d_in[2];
    const float* qkv_b = (const float*)d_in[3];
    const float* out_w = (const float*)d_in[4];
    const float* out_b = (const float*)d_in[5];
    const int*   mask  = (const int*)d_in[6];
    float* out = (float*)d_out;

    char* wp = (char*)d_ws;
    auto alloc = [&](size_t bytes) {
        char* p = wp;
        wp += (bytes + 255) & ~(size_t)255;
        return p;
    };
    unsigned short* xb   = (unsigned short*)alloc((size_t)Bb * Ls * DM * 2);
    unsigned short* wqb  = (unsigned short*)alloc((size_t)QKV * DM * 2);
    unsigned short* wob  = (unsigned short*)alloc((size_t)DM * DM * 2);
    unsigned short* ebb  = (unsigned short*)alloc((size_t)NH * Ls * Ls * 2);
    float*          tab  = (float*)alloc((size_t)Ls * DH * 4);
    unsigned short* qsb  = (unsigned short*)alloc((size_t)Bb * NH * Ls * DH * 2);
    unsigned short* ksb  = (unsigned short*)alloc((size_t)Bb * NH * Ls * DH * 2);
    unsigned short* vtb  = (unsigned short*)alloc((size_t)Bb * NH * DH * Ls * 2);
    unsigned short* obb  = (unsigned short*)alloc((size_t)Bb * Ls * DM * 2);

    prep_kernel<<<dim3(2048), dim3(256), 0, stream>>>(x, qkv_w, out_w, posb, xb, wqb, wob, ebb, tab);
    gemm_qkv<<<dim3(1152), dim3(256), 0, stream>>>(wqb, xb, qkv_b, tab, qsb, ksb, vtb);
    attn_kernel<<<dim3(1536), dim3(256), 0, stream>>>(qsb, ksb, vtb, ebb, mask, obb);
    gemm_nt<0><<<dim3(384), dim3(256), 0, stream>>>(obb, wob, out_b, (void*)out, Bb * Ls, DM, DM);
}